// Round 2
// baseline (549.383 us; speedup 1.0000x reference)
//
#include <hip/hip_runtime.h>
#include <hip/hip_bf16.h>
#include <math.h>

#define NF 256
#define NH 64
#define NC 16
#define NPART 8   // CSR partitions, mapped to XCDs via blockIdx&7 (perf heuristic only)

// ---------------- degree count (partitioned) ----------------
// partition p = blockIdx&7; identical grid/block as k_fill so edge->p matches.
__global__ void k_count(const int* __restrict__ dst, int* __restrict__ cnt8, int E, int N) {
    int i = blockIdx.x * 256 + threadIdx.x;
    int p = blockIdx.x & (NPART - 1);
    if (i < E) atomicAdd(&cnt8[p * N + dst[i]], 1);
}

// dinv[v] = rsqrt(total_indeg + 1)  (self-loop included in degree)
__global__ void k_dinv(const int* __restrict__ cnt8, float* __restrict__ dinv, int n) {
    int i = blockIdx.x * 256 + threadIdx.x;
    if (i < n) {
        int d = 1;
        #pragma unroll
        for (int p = 0; p < NPART; ++p) d += cnt8[p * n + i];
        dinv[i] = rsqrtf((float)d);
    }
}

// ---------------- exclusive scan over 8N entries (3 kernels, 1024-blocks) ------
__global__ void k_scan1(const int* __restrict__ cnt, int* __restrict__ rowptr,
                        int* __restrict__ bsums, int M) {
    __shared__ int s[1024];
    int t = threadIdx.x;
    int i = blockIdx.x * 1024 + t;
    int v = (i < M) ? cnt[i] : 0;
    s[t] = v;
    __syncthreads();
    for (int off = 1; off < 1024; off <<= 1) {
        int add = (t >= off) ? s[t - off] : 0;
        __syncthreads();
        s[t] += add;
        __syncthreads();
    }
    if (i < M) rowptr[i] = s[t] - v;            // block-local exclusive
    if (t == 1023) bsums[blockIdx.x] = s[1023]; // block total
}

__global__ void k_scan2(int* __restrict__ bsums, int nb) {
    __shared__ int s[1024];
    int t = threadIdx.x;
    int v = (t < nb) ? bsums[t] : 0;
    s[t] = v;
    __syncthreads();
    for (int off = 1; off < 1024; off <<= 1) {
        int add = (t >= off) ? s[t - off] : 0;
        __syncthreads();
        s[t] += add;
        __syncthreads();
    }
    if (t < nb) bsums[t] = s[t] - v;  // exclusive scan of block sums
}

__global__ void k_scan3(int* __restrict__ rowptr, const int* __restrict__ bsums,
                        int* __restrict__ cursor, int M) {
    int i = blockIdx.x * 1024 + threadIdx.x;
    if (i < M) {
        int r = rowptr[i] + bsums[blockIdx.x];
        rowptr[i] = r;
        cursor[i] = r;
    }
}

// ---------------- CSR fill (partitioned: XCD-local, line-dense writes) ---------
__global__ void k_fill(const int* __restrict__ src, const int* __restrict__ dst,
                       int* __restrict__ cursor8, int* __restrict__ esrc, int E, int N) {
    int i = blockIdx.x * 256 + threadIdx.x;
    int p = blockIdx.x & (NPART - 1);
    if (i < E) {
        int d = dst[i];
        int pos = atomicAdd(&cursor8[p * N + d], 1);
        esrc[pos] = src[i];
    }
}

// ---------------- GEMM1: h1 = x @ W1   [n,256]x[256,64] ----------------
__global__ void k_gemm1(const float* __restrict__ x, const float* __restrict__ W1,
                        float* __restrict__ h1, int n) {
    __shared__ float As[16][64];  // x tile transposed: [k][m]
    __shared__ float Bs[16][64];  // W1 tile: [k][col]
    int tid = threadIdx.x;
    int tx = tid & 15;   // col group
    int ty = tid >> 4;   // row group
    int m0 = blockIdx.x * 64;
    float acc[4][4] = {{0.f}};

    for (int k0 = 0; k0 < NF; k0 += 16) {
        {
            int lm = tid >> 2;
            int lk4 = (tid & 3) * 4;
            int node = m0 + lm;
            float4 xv = make_float4(0.f, 0.f, 0.f, 0.f);
            if (node < n) xv = *(const float4*)&x[(size_t)node * NF + k0 + lk4];
            As[lk4 + 0][lm] = xv.x;
            As[lk4 + 1][lm] = xv.y;
            As[lk4 + 2][lm] = xv.z;
            As[lk4 + 3][lm] = xv.w;
        }
        #pragma unroll
        for (int r = 0; r < 4; ++r) {
            int idx = tid + r * 256;
            int kk = idx >> 6;
            int col = idx & 63;
            Bs[kk][col] = W1[(size_t)(k0 + kk) * NH + col];
        }
        __syncthreads();
        #pragma unroll
        for (int kk = 0; kk < 16; ++kk) {
            float4 a = *(const float4*)&As[kk][4 * ty];
            float4 b = *(const float4*)&Bs[kk][4 * tx];
            float av[4] = {a.x, a.y, a.z, a.w};
            float bv[4] = {b.x, b.y, b.z, b.w};
            #pragma unroll
            for (int i = 0; i < 4; ++i)
                #pragma unroll
                for (int j = 0; j < 4; ++j)
                    acc[i][j] = fmaf(av[i], bv[j], acc[i][j]);
        }
        __syncthreads();
    }
    #pragma unroll
    for (int i = 0; i < 4; ++i) {
        int node = m0 + 4 * ty + i;
        if (node < n) {
            float4 o = make_float4(acc[i][0], acc[i][1], acc[i][2], acc[i][3]);
            *(float4*)&h1[(size_t)node * NH + 4 * tx] = o;
        }
    }
}

// ---------------- agg1: h1agg = relu( D^-1/2 (A+I) D^-1/2 h1 + b1 ) ------------
// wave per node, lane per feature (64); walks 8 partition segments
__global__ void k_agg1(const float* __restrict__ h1, const float* __restrict__ dinv,
                       const int* __restrict__ rowptr8, const int* __restrict__ cnt8,
                       const int* __restrict__ esrc, const float* __restrict__ b1,
                       float* __restrict__ h1agg, int n) {
    int wave = threadIdx.x >> 6;
    int lane = threadIdx.x & 63;
    int v = blockIdx.x * 4 + wave;
    if (v >= n) return;
    float dv = dinv[v];
    float acc = dv * dv * h1[(size_t)v * NH + lane];
    #pragma unroll
    for (int p = 0; p < NPART; ++p) {
        int idx = p * n + v;
        int e = rowptr8[idx];
        int end = e + cnt8[idx];
        for (; e + 1 < end; e += 2) {
            int s0 = esrc[e];
            int s1 = esrc[e + 1];
            float w0 = dinv[s0] * dv;
            float w1 = dinv[s1] * dv;
            float v0 = h1[(size_t)s0 * NH + lane];
            float v1 = h1[(size_t)s1 * NH + lane];
            acc = fmaf(w0, v0, acc);
            acc = fmaf(w1, v1, acc);
        }
        if (e < end) {
            int s0 = esrc[e];
            acc = fmaf(dinv[s0] * dv, h1[(size_t)s0 * NH + lane], acc);
        }
    }
    acc += b1[lane];
    h1agg[(size_t)v * NH + lane] = fmaxf(acc, 0.f);
}

// ---------------- GEMM2: g = h1agg @ W2   [n,64]x[64,16] ----------------
__global__ void k_gemm2(const float* __restrict__ h1agg, const float* __restrict__ W2,
                        float* __restrict__ g, int n) {
    __shared__ float W2s[NH * NC];
    {
        int t = threadIdx.x;
        #pragma unroll
        for (int r = 0; r < 4; ++r) W2s[t + r * 256] = W2[t + r * 256];
    }
    __syncthreads();
    int grp = threadIdx.x >> 4;
    int c = threadIdx.x & 15;
    int v = blockIdx.x * 16 + grp;
    if (v >= n) return;
    float acc = 0.f;
    const float* row = &h1agg[(size_t)v * NH];
    #pragma unroll
    for (int k4 = 0; k4 < NH; k4 += 4) {
        float4 h = *(const float4*)&row[k4];
        acc = fmaf(h.x, W2s[(k4 + 0) * NC + c], acc);
        acc = fmaf(h.y, W2s[(k4 + 1) * NC + c], acc);
        acc = fmaf(h.z, W2s[(k4 + 2) * NC + c], acc);
        acc = fmaf(h.w, W2s[(k4 + 3) * NC + c], acc);
    }
    g[(size_t)v * NC + c] = acc;
}

// ---------------- agg2 + bias + log_softmax ----------------
// 16 lanes per node; walks 8 partition segments
__global__ void k_agg2(const float* __restrict__ g, const float* __restrict__ dinv,
                       const int* __restrict__ rowptr8, const int* __restrict__ cnt8,
                       const int* __restrict__ esrc, const float* __restrict__ b2,
                       float* __restrict__ out, int n) {
    int grp = threadIdx.x >> 4;
    int lane = threadIdx.x & 15;
    int v = blockIdx.x * 16 + grp;
    if (v >= n) return;
    float dv = dinv[v];
    float acc = dv * dv * g[(size_t)v * NC + lane];
    #pragma unroll
    for (int p = 0; p < NPART; ++p) {
        int idx = p * n + v;
        int e = rowptr8[idx];
        int end = e + cnt8[idx];
        for (; e + 1 < end; e += 2) {
            int s0 = esrc[e];
            int s1 = esrc[e + 1];
            float w0 = dinv[s0] * dv;
            float w1 = dinv[s1] * dv;
            float v0 = g[(size_t)s0 * NC + lane];
            float v1 = g[(size_t)s1 * NC + lane];
            acc = fmaf(w0, v0, acc);
            acc = fmaf(w1, v1, acc);
        }
        if (e < end) {
            int s0 = esrc[e];
            acc = fmaf(dinv[s0] * dv, g[(size_t)s0 * NC + lane], acc);
        }
    }
    acc += b2[lane];
    // log_softmax over 16 lanes
    float m = acc;
    #pragma unroll
    for (int mask = 1; mask < 16; mask <<= 1)
        m = fmaxf(m, __shfl_xor(m, mask, 16));
    float ex = __expf(acc - m);
    float ssum = ex;
    #pragma unroll
    for (int mask = 1; mask < 16; mask <<= 1)
        ssum += __shfl_xor(ssum, mask, 16);
    out[(size_t)v * NC + lane] = acc - m - __logf(ssum);
}

extern "C" void kernel_launch(void* const* d_in, const int* in_sizes, int n_in,
                              void* d_out, int out_size, void* d_ws, size_t ws_size,
                              hipStream_t stream) {
    const float* x  = (const float*)d_in[0];
    const int*   ei = (const int*)d_in[1];
    const float* W1 = (const float*)d_in[2];
    const float* b1 = (const float*)d_in[3];
    const float* W2 = (const float*)d_in[4];
    const float* b2 = (const float*)d_in[5];
    float* out = (float*)d_out;

    const int N = in_sizes[0] / NF;
    const int E = in_sizes[1] / 2;
    const int M = NPART * N;           // partitioned count/rowptr length
    const int* src = ei;
    const int* dst = ei + E;

    // workspace layout
    char* ws = (char*)d_ws;
    size_t o = 0;
    int*   cnt8    = (int*)(ws + o);   o += (size_t)M * 4;            // 3.2 MB
    int*   rowptr8 = (int*)(ws + o);   o += (size_t)M * 4;            // 3.2 MB
    float* dinv    = (float*)(ws + o); o += (size_t)N * 4;            // 0.4 MB
    int*   bsums   = (int*)(ws + o);   o += 4096;
    int*   esrc    = (int*)(ws + o);   o += (size_t)E * 4 + 1024;     // 6.4 MB
    float* h1      = (float*)(ws + o); o += (size_t)N * NH * 4;       // 25.6 MB
    float* h1agg   = (float*)(ws + o); o += (size_t)N * NH * 4;       // 25.6 MB
    float* g       = h1;               // alias: h1 dead after agg1
    int*   cursor8 = (int*)h1agg;      // alias: cursor dead before h1agg written

    hipMemsetAsync(cnt8, 0, (size_t)M * 4, stream);

    int gE  = (E + 255) / 256;
    int gN  = (N + 255) / 256;
    int nbM = (M + 1023) / 1024;       // scan blocks over 8N (<=1024)

    k_count<<<gE, 256, 0, stream>>>(dst, cnt8, E, N);
    k_dinv<<<gN, 256, 0, stream>>>(cnt8, dinv, N);
    k_scan1<<<nbM, 1024, 0, stream>>>(cnt8, rowptr8, bsums, M);
    k_scan2<<<1, 1024, 0, stream>>>(bsums, nbM);
    k_scan3<<<nbM, 1024, 0, stream>>>(rowptr8, bsums, cursor8, M);
    k_fill<<<gE, 256, 0, stream>>>(src, dst, cursor8, esrc, E, N);

    k_gemm1<<<(N + 63) / 64, 256, 0, stream>>>(x, W1, h1, N);
    k_agg1<<<(N + 3) / 4, 256, 0, stream>>>(h1, dinv, rowptr8, cnt8, esrc, b1, h1agg, N);
    k_gemm2<<<(N + 15) / 16, 256, 0, stream>>>(h1agg, W2, g, N);
    k_agg2<<<(N + 15) / 16, 256, 0, stream>>>(g, dinv, rowptr8, cnt8, esrc, b2, out, N);
}

// Round 3
// 470.911 us; speedup vs baseline: 1.1666x; 1.1666x over previous
//
#include <hip/hip_runtime.h>
#include <hip/hip_bf16.h>
#include <math.h>

#define NF 256
#define NH 64
#define NC 16
#define NPART 8   // CSR partitions, mapped to XCDs via blockIdx&7 (perf heuristic only)

// ---------------- degree count (partitioned) ----------------
__global__ void k_count(const int* __restrict__ dst, int* __restrict__ cnt8, int E, int N) {
    int i = blockIdx.x * 256 + threadIdx.x;
    int p = blockIdx.x & (NPART - 1);
    if (i < E) atomicAdd(&cnt8[p * N + dst[i]], 1);
}

// dinv[v] = rsqrt(indeg+1); also emit total per-node count for the node-major scan
__global__ void k_dinv(const int* __restrict__ cnt8, float* __restrict__ dinv,
                       int* __restrict__ cnt_tot, int n) {
    int i = blockIdx.x * 256 + threadIdx.x;
    if (i < n) {
        int d = 0;
        #pragma unroll
        for (int p = 0; p < NPART; ++p) d += cnt8[p * n + i];
        cnt_tot[i] = d;
        dinv[i] = rsqrtf((float)(d + 1));
    }
}

// ---------------- exclusive scan (3 kernels, 1024-wide blocks) ----------------
__global__ void k_scan1(const int* __restrict__ cnt, int* __restrict__ rowptr,
                        int* __restrict__ bsums, int M) {
    __shared__ int s[1024];
    int t = threadIdx.x;
    int i = blockIdx.x * 1024 + t;
    int v = (i < M) ? cnt[i] : 0;
    s[t] = v;
    __syncthreads();
    for (int off = 1; off < 1024; off <<= 1) {
        int add = (t >= off) ? s[t - off] : 0;
        __syncthreads();
        s[t] += add;
        __syncthreads();
    }
    if (i < M) rowptr[i] = s[t] - v;
    if (t == 1023) bsums[blockIdx.x] = s[1023];
}

__global__ void k_scan2(int* __restrict__ bsums, int nb) {
    __shared__ int s[1024];
    int t = threadIdx.x;
    int v = (t < nb) ? bsums[t] : 0;
    s[t] = v;
    __syncthreads();
    for (int off = 1; off < 1024; off <<= 1) {
        int add = (t >= off) ? s[t - off] : 0;
        __syncthreads();
        s[t] += add;
        __syncthreads();
    }
    if (t < nb) bsums[t] = s[t] - v;
}

__global__ void k_scan3(int* __restrict__ rowptr, const int* __restrict__ bsums,
                        int* __restrict__ cursor, int M) {
    int i = blockIdx.x * 1024 + threadIdx.x;
    if (i < M) {
        int r = rowptr[i] + bsums[blockIdx.x];
        rowptr[i] = r;
        if (cursor) cursor[i] = r;
    }
}

// ---------------- CSR fill (partitioned: XCD-local, line-dense writes) ---------
__global__ void k_fill(const int* __restrict__ src, const int* __restrict__ dst,
                       int* __restrict__ cursor8, int* __restrict__ esrc8, int E, int N) {
    int i = blockIdx.x * 256 + threadIdx.x;
    int p = blockIdx.x & (NPART - 1);
    if (i < E) {
        int d = dst[i];
        int pos = atomicAdd(&cursor8[p * N + d], 1);
        esrc8[pos] = src[i];
    }
}

// ---------------- repack: p-major CSR -> node-major CSR + per-edge weight ------
__global__ void k_repack(const int* __restrict__ esrc8, const int* __restrict__ rowptr8,
                         const int* __restrict__ cnt8, const int* __restrict__ rowptr_tot,
                         const float* __restrict__ dinv, int* __restrict__ esrc,
                         float* __restrict__ wsrc, int n) {
    int v = blockIdx.x * 256 + threadIdx.x;
    if (v >= n) return;
    int wpos = rowptr_tot[v];
    #pragma unroll
    for (int p = 0; p < NPART; ++p) {
        int b = rowptr8[p * n + v];
        int c = cnt8[p * n + v];
        for (int i = 0; i < c; ++i) {
            int s = esrc8[b + i];
            esrc[wpos] = s;
            wsrc[wpos] = dinv[s];
            ++wpos;
        }
    }
}

// ---------------- GEMM1: h1 = x @ W1   [n,256]x[256,64] ----------------
__global__ void k_gemm1(const float* __restrict__ x, const float* __restrict__ W1,
                        float* __restrict__ h1, int n) {
    __shared__ float As[16][64];
    __shared__ float Bs[16][64];
    int tid = threadIdx.x;
    int tx = tid & 15;
    int ty = tid >> 4;
    int m0 = blockIdx.x * 64;
    float acc[4][4] = {{0.f}};

    for (int k0 = 0; k0 < NF; k0 += 16) {
        {
            int lm = tid >> 2;
            int lk4 = (tid & 3) * 4;
            int node = m0 + lm;
            float4 xv = make_float4(0.f, 0.f, 0.f, 0.f);
            if (node < n) xv = *(const float4*)&x[(size_t)node * NF + k0 + lk4];
            As[lk4 + 0][lm] = xv.x;
            As[lk4 + 1][lm] = xv.y;
            As[lk4 + 2][lm] = xv.z;
            As[lk4 + 3][lm] = xv.w;
        }
        #pragma unroll
        for (int r = 0; r < 4; ++r) {
            int idx = tid + r * 256;
            int kk = idx >> 6;
            int col = idx & 63;
            Bs[kk][col] = W1[(size_t)(k0 + kk) * NH + col];
        }
        __syncthreads();
        #pragma unroll
        for (int kk = 0; kk < 16; ++kk) {
            float4 a = *(const float4*)&As[kk][4 * ty];
            float4 b = *(const float4*)&Bs[kk][4 * tx];
            float av[4] = {a.x, a.y, a.z, a.w};
            float bv[4] = {b.x, b.y, b.z, b.w};
            #pragma unroll
            for (int i = 0; i < 4; ++i)
                #pragma unroll
                for (int j = 0; j < 4; ++j)
                    acc[i][j] = fmaf(av[i], bv[j], acc[i][j]);
        }
        __syncthreads();
    }
    #pragma unroll
    for (int i = 0; i < 4; ++i) {
        int node = m0 + 4 * ty + i;
        if (node < n) {
            float4 o = make_float4(acc[i][0], acc[i][1], acc[i][2], acc[i][3]);
            *(float4*)&h1[(size_t)node * NH + 4 * tx] = o;
        }
    }
}

// ---------------- agg1: wave/node, coop edge load, batch-8 independent gathers --
__global__ void k_agg1(const float* __restrict__ h1, const float* __restrict__ dinv,
                       const int* __restrict__ rowptr_tot, const int* __restrict__ cnt_tot,
                       const int* __restrict__ esrc, const float* __restrict__ wsrc,
                       const float* __restrict__ b1, float* __restrict__ h1agg, int n) {
    int wave = threadIdx.x >> 6;
    int lane = threadIdx.x & 63;
    int v = blockIdx.x * 4 + wave;
    if (v >= n) return;
    float dv = dinv[v];
    float acc = dv * dv * h1[(size_t)v * NH + lane];
    int beg = rowptr_tot[v];
    int end = beg + cnt_tot[v];
    for (int base = beg; base < end; base += 64) {
        int cnt = end - base;
        if (cnt > 64) cnt = 64;
        int s = 0;
        float w = 0.f;
        if (lane < cnt) {
            s = esrc[base + lane];
            w = wsrc[base + lane] * dv;
        }
        int j = 0;
        for (; j + 8 <= cnt; j += 8) {
            float vals[8], ww[8];
            #pragma unroll
            for (int u = 0; u < 8; ++u) {
                int sj = __shfl(s, j + u);
                ww[u] = __shfl(w, j + u);
                vals[u] = h1[(size_t)sj * NH + lane];
            }
            #pragma unroll
            for (int u = 0; u < 8; ++u) acc = fmaf(ww[u], vals[u], acc);
        }
        if (j < cnt) {
            float vals[8], ww[8];
            #pragma unroll
            for (int u = 0; u < 8; ++u) {
                int idx = j + u;
                int pick = (idx < cnt) ? idx : 0;
                int sj = __shfl(s, pick);
                float wv = __shfl(w, pick);
                ww[u] = (idx < cnt) ? wv : 0.f;
                vals[u] = h1[(size_t)sj * NH + lane];
            }
            #pragma unroll
            for (int u = 0; u < 8; ++u) acc = fmaf(ww[u], vals[u], acc);
        }
    }
    acc += b1[lane];
    h1agg[(size_t)v * NH + lane] = fmaxf(acc, 0.f);
}

// ---------------- GEMM2: g = h1agg @ W2   [n,64]x[64,16] ----------------
__global__ void k_gemm2(const float* __restrict__ h1agg, const float* __restrict__ W2,
                        float* __restrict__ g, int n) {
    __shared__ float W2s[NH * NC];
    {
        int t = threadIdx.x;
        #pragma unroll
        for (int r = 0; r < 4; ++r) W2s[t + r * 256] = W2[t + r * 256];
    }
    __syncthreads();
    int grp = threadIdx.x >> 4;
    int c = threadIdx.x & 15;
    int v = blockIdx.x * 16 + grp;
    if (v >= n) return;
    float acc = 0.f;
    const float* row = &h1agg[(size_t)v * NH];
    #pragma unroll
    for (int k4 = 0; k4 < NH; k4 += 4) {
        float4 h = *(const float4*)&row[k4];
        acc = fmaf(h.x, W2s[(k4 + 0) * NC + c], acc);
        acc = fmaf(h.y, W2s[(k4 + 1) * NC + c], acc);
        acc = fmaf(h.z, W2s[(k4 + 2) * NC + c], acc);
        acc = fmaf(h.w, W2s[(k4 + 3) * NC + c], acc);
    }
    g[(size_t)v * NC + c] = acc;
}

// ---------------- agg2 + bias + log_softmax: 16-lane group/node, batch-8 -------
__global__ void k_agg2(const float* __restrict__ g, const float* __restrict__ dinv,
                       const int* __restrict__ rowptr_tot, const int* __restrict__ cnt_tot,
                       const int* __restrict__ esrc, const float* __restrict__ wsrc,
                       const float* __restrict__ b2, float* __restrict__ out, int n) {
    int grp = threadIdx.x >> 4;
    int lane = threadIdx.x & 15;
    int v = blockIdx.x * 16 + grp;
    if (v >= n) return;
    float dv = dinv[v];
    float acc = dv * dv * g[(size_t)v * NC + lane];
    int beg = rowptr_tot[v];
    int end = beg + cnt_tot[v];
    for (int base = beg; base < end; base += 16) {
        int cnt = end - base;
        if (cnt > 16) cnt = 16;
        int s = 0;
        float w = 0.f;
        if (lane < cnt) {
            s = esrc[base + lane];
            w = wsrc[base + lane] * dv;
        }
        int j = 0;
        for (; j + 8 <= cnt; j += 8) {
            float vals[8], ww[8];
            #pragma unroll
            for (int u = 0; u < 8; ++u) {
                int sj = __shfl(s, j + u, 16);
                ww[u] = __shfl(w, j + u, 16);
                vals[u] = g[(size_t)sj * NC + lane];
            }
            #pragma unroll
            for (int u = 0; u < 8; ++u) acc = fmaf(ww[u], vals[u], acc);
        }
        if (j < cnt) {
            float vals[8], ww[8];
            #pragma unroll
            for (int u = 0; u < 8; ++u) {
                int idx = j + u;
                int pick = (idx < cnt) ? idx : 0;
                int sj = __shfl(s, pick, 16);
                float wv = __shfl(w, pick, 16);
                ww[u] = (idx < cnt) ? wv : 0.f;
                vals[u] = g[(size_t)sj * NC + lane];
            }
            #pragma unroll
            for (int u = 0; u < 8; ++u) acc = fmaf(ww[u], vals[u], acc);
        }
    }
    acc += b2[lane];
    // log_softmax over 16 lanes
    float m = acc;
    #pragma unroll
    for (int mask = 1; mask < 16; mask <<= 1)
        m = fmaxf(m, __shfl_xor(m, mask, 16));
    float ex = __expf(acc - m);
    float ssum = ex;
    #pragma unroll
    for (int mask = 1; mask < 16; mask <<= 1)
        ssum += __shfl_xor(ssum, mask, 16);
    out[(size_t)v * NC + lane] = acc - m - __logf(ssum);
}

extern "C" void kernel_launch(void* const* d_in, const int* in_sizes, int n_in,
                              void* d_out, int out_size, void* d_ws, size_t ws_size,
                              hipStream_t stream) {
    const float* x  = (const float*)d_in[0];
    const int*   ei = (const int*)d_in[1];
    const float* W1 = (const float*)d_in[2];
    const float* b1 = (const float*)d_in[3];
    const float* W2 = (const float*)d_in[4];
    const float* b2 = (const float*)d_in[5];
    float* out = (float*)d_out;

    const int N = in_sizes[0] / NF;
    const int E = in_sizes[1] / 2;
    const int M = NPART * N;
    const int* src = ei;
    const int* dst = ei + E;

    // workspace layout (regions A/B reused across phases; same-stream ordering)
    char* ws = (char*)d_ws;
    size_t o = 0;
    int*   cnt8       = (int*)(ws + o);   o += (size_t)M * 4;        // 3.2 MB
    int*   rowptr8    = (int*)(ws + o);   o += (size_t)M * 4;        // 3.2 MB
    int*   cnt_tot    = (int*)(ws + o);   o += (size_t)N * 4;        // 0.4 MB
    int*   rowptr_tot = (int*)(ws + o);   o += (size_t)N * 4;        // 0.4 MB
    float* dinv       = (float*)(ws + o); o += (size_t)N * 4;        // 0.4 MB
    int*   bsums      = (int*)(ws + o);   o += 4096;
    int*   bsums2     = (int*)(ws + o);   o += 4096;
    int*   esrc       = (int*)(ws + o);   o += (size_t)E * 4;        // 6.4 MB
    float* wsrc       = (float*)(ws + o); o += (size_t)E * 4;        // 6.4 MB
    char*  regionA    = ws + o;           o += (size_t)N * NH * 4;   // 25.6 MB
    char*  regionB    = ws + o;           o += (size_t)N * NH * 4;   // 25.6 MB
    int*   esrc8   = (int*)regionA;   // fill/repack phase
    float* h1      = (float*)regionA; // gemm1 onward (esrc8 dead)
    float* g       = (float*)regionA; // gemm2 onward (h1 dead)
    int*   cursor8 = (int*)regionB;   // scan3/fill phase
    float* h1agg   = (float*)regionB; // agg1 onward (cursor8 dead)

    hipMemsetAsync(cnt8, 0, (size_t)M * 4, stream);

    int gE  = (E + 255) / 256;
    int gN  = (N + 255) / 256;
    int nbM = (M + 1023) / 1024;
    int nbN = (N + 1023) / 1024;

    k_count<<<gE, 256, 0, stream>>>(dst, cnt8, E, N);
    k_dinv<<<gN, 256, 0, stream>>>(cnt8, dinv, cnt_tot, N);
    // scan p-major counts -> fill cursors
    k_scan1<<<nbM, 1024, 0, stream>>>(cnt8, rowptr8, bsums, M);
    k_scan2<<<1, 1024, 0, stream>>>(bsums, nbM);
    k_scan3<<<nbM, 1024, 0, stream>>>(rowptr8, bsums, cursor8, M);
    // scan node-major totals -> rowptr_tot
    k_scan1<<<nbN, 1024, 0, stream>>>(cnt_tot, rowptr_tot, bsums2, N);
    k_scan2<<<1, 1024, 0, stream>>>(bsums2, nbN);
    k_scan3<<<nbN, 1024, 0, stream>>>(rowptr_tot, bsums2, (int*)nullptr, N);

    k_fill<<<gE, 256, 0, stream>>>(src, dst, cursor8, esrc8, E, N);
    k_repack<<<gN, 256, 0, stream>>>(esrc8, rowptr8, cnt8, rowptr_tot, dinv, esrc, wsrc, N);

    k_gemm1<<<(N + 63) / 64, 256, 0, stream>>>(x, W1, h1, N);
    k_agg1<<<(N + 3) / 4, 256, 0, stream>>>(h1, dinv, rowptr_tot, cnt_tot, esrc, wsrc, b1, h1agg, N);
    k_gemm2<<<(N + 15) / 16, 256, 0, stream>>>(h1agg, W2, g, N);
    k_agg2<<<(N + 15) / 16, 256, 0, stream>>>(g, dinv, rowptr_tot, cnt_tot, esrc, wsrc, b2, out, N);
}

// Round 4
// 469.552 us; speedup vs baseline: 1.1700x; 1.0029x over previous
//
#include <hip/hip_runtime.h>
#include <hip/hip_bf16.h>
#include <math.h>

#define NF 256
#define NH 64
#define NC 16
#define NPART 8   // CSR partitions (p = blockIdx&7) — perf heuristic only

typedef __attribute__((ext_vector_type(8))) __bf16 bf16x8;
typedef __attribute__((ext_vector_type(4))) float f32x4;
typedef __attribute__((ext_vector_type(8))) short short8;

__device__ __forceinline__ unsigned short f2bf(float v) {   // RNE fp32->bf16
    unsigned u = __float_as_uint(v);
    unsigned r = u + 0x7fffu + ((u >> 16) & 1u);
    return (unsigned short)(r >> 16);
}
__device__ __forceinline__ float bf2f(unsigned short s) {
    return __uint_as_float(((unsigned)s) << 16);
}

// ---------------- degree count (partitioned) ----------------
__global__ void k_count(const int* __restrict__ dst, int* __restrict__ cnt8, int E, int N) {
    int i = blockIdx.x * 256 + threadIdx.x;
    int p = blockIdx.x & (NPART - 1);
    if (i < E) atomicAdd(&cnt8[p * N + dst[i]], 1);
}

// dinv[v] = rsqrt(indeg+1); also total per-node count
__global__ void k_dinv(const int* __restrict__ cnt8, float* __restrict__ dinv,
                       int* __restrict__ cnt_tot, int n) {
    int i = blockIdx.x * 256 + threadIdx.x;
    if (i < n) {
        int d = 0;
        #pragma unroll
        for (int p = 0; p < NPART; ++p) d += cnt8[p * n + i];
        cnt_tot[i] = d;
        dinv[i] = rsqrtf((float)(d + 1));
    }
}

// ---------------- exclusive scan over N (3 kernels) ----------------
__global__ void k_scan1(const int* __restrict__ cnt, int* __restrict__ rowptr,
                        int* __restrict__ bsums, int M) {
    __shared__ int s[1024];
    int t = threadIdx.x;
    int i = blockIdx.x * 1024 + t;
    int v = (i < M) ? cnt[i] : 0;
    s[t] = v;
    __syncthreads();
    for (int off = 1; off < 1024; off <<= 1) {
        int add = (t >= off) ? s[t - off] : 0;
        __syncthreads();
        s[t] += add;
        __syncthreads();
    }
    if (i < M) rowptr[i] = s[t] - v;
    if (t == 1023) bsums[blockIdx.x] = s[1023];
}

__global__ void k_scan2(int* __restrict__ bsums, int nb) {
    __shared__ int s[1024];
    int t = threadIdx.x;
    int v = (t < nb) ? bsums[t] : 0;
    s[t] = v;
    __syncthreads();
    for (int off = 1; off < 1024; off <<= 1) {
        int add = (t >= off) ? s[t - off] : 0;
        __syncthreads();
        s[t] += add;
        __syncthreads();
    }
    if (t < nb) bsums[t] = s[t] - v;
}

__global__ void k_scan3(int* __restrict__ rowptr, const int* __restrict__ bsums, int M) {
    int i = blockIdx.x * 1024 + threadIdx.x;
    if (i < M) rowptr[i] += bsums[blockIdx.x];
}

// ---------------- cursors: p-major storage, node-major target offsets ----------
// cursor8[p*N+v] = rowptr_tot[v] + sum_{p'<p} cnt8[p'*N+v]  -> fill writes land
// directly in node-major esrc; no repack needed.
__global__ void k_cursor(const int* __restrict__ cnt8, const int* __restrict__ rowptr_tot,
                         int* __restrict__ cursor8, int n) {
    int v = blockIdx.x * 256 + threadIdx.x;
    if (v >= n) return;
    int run = rowptr_tot[v];
    #pragma unroll
    for (int p = 0; p < NPART; ++p) {
        cursor8[p * n + v] = run;
        run += cnt8[p * n + v];
    }
}

// ---------------- CSR fill (XCD-partitioned cursors, node-major esrc) ----------
__global__ void k_fill(const int* __restrict__ src, const int* __restrict__ dst,
                       int* __restrict__ cursor8, int* __restrict__ esrc, int E, int N) {
    int i = blockIdx.x * 256 + threadIdx.x;
    int p = blockIdx.x & (NPART - 1);
    if (i < E) {
        int d = dst[i];
        int pos = atomicAdd(&cursor8[p * N + d], 1);
        esrc[pos] = src[i];
    }
}

// ---------------- per-edge weight: wsrc[i] = dinv[esrc[i]] ----------------
__global__ void k_wsrc(const int* __restrict__ esrc, const float* __restrict__ dinv,
                       float* __restrict__ wsrc, int E) {
    int i = blockIdx.x * 256 + threadIdx.x;
    if (i < E) wsrc[i] = dinv[esrc[i]];
}

// ---------------- GEMM1 (MFMA bf16 hi/lo split): h1 = x @ W1 -------------------
// block = 256 thr (4 waves), tile 64 rows x 64 cols, K-loop step 32.
// A/B staged in LDS in MFMA fragment order (lane*16B) -> conflict-free reads.
__global__ __launch_bounds__(256) void k_gemm1(const float* __restrict__ x,
                                               const float* __restrict__ W1,
                                               float* __restrict__ h1, int n) {
    __shared__ __align__(16) unsigned short Ah[2048], Al[2048], Bh[2048], Bl[2048];
    int tid = threadIdx.x;
    int lane = tid & 63;
    int wid = tid >> 6;          // rowgroup 0..3
    int m0 = blockIdx.x * 64;
    f32x4 acc[4] = {{0.f, 0.f, 0.f, 0.f}, {0.f, 0.f, 0.f, 0.f},
                    {0.f, 0.f, 0.f, 0.f}, {0.f, 0.f, 0.f, 0.f}};

    int bcol = tid & 63;
    int bkq = tid >> 6;          // k-quad 0..3
    int bIdx = ((bcol >> 4) * 512) + (((bkq << 4) | (bcol & 15)) * 8);  // shorts

    for (int k0 = 0; k0 < NF; k0 += 32) {
        // stage A: 64 rows x 32 k fp32 -> hi/lo bf16 fragments
        #pragma unroll
        for (int it = 0; it < 2; ++it) {
            int f = tid + it * 256;
            int m = f >> 3;          // row in tile
            int g = f & 7;           // float4 index in the 32-k row
            int node = m0 + m;
            float4 xv = make_float4(0.f, 0.f, 0.f, 0.f);
            if (node < n) xv = *(const float4*)&x[(size_t)node * NF + k0 + g * 4];
            ushort4 hi, lo;
            hi.x = f2bf(xv.x); lo.x = f2bf(xv.x - bf2f(hi.x));
            hi.y = f2bf(xv.y); lo.y = f2bf(xv.y - bf2f(hi.y));
            hi.z = f2bf(xv.z); lo.z = f2bf(xv.z - bf2f(hi.z));
            hi.w = f2bf(xv.w); lo.w = f2bf(xv.w - bf2f(hi.w));
            // frag: lane=((k/8)<<4)|(m&15), byte j=k%8; here k=g*4..g*4+3
            int aIdx = ((m >> 4) * 512) + ((((g >> 1) << 4) | (m & 15)) * 8) + (g & 1) * 4;
            *(ushort4*)&Ah[aIdx] = hi;
            *(ushort4*)&Al[aIdx] = lo;
        }
        // stage B: 32 k x 64 col; thread owns (col, k-quad) = one fragment lane
        {
            unsigned short hb[8], lb[8];
            #pragma unroll
            for (int j = 0; j < 8; ++j) {
                float w = W1[(size_t)(k0 + bkq * 8 + j) * NH + bcol];
                hb[j] = f2bf(w);
                lb[j] = f2bf(w - bf2f(hb[j]));
            }
            #pragma unroll
            for (int j = 0; j < 8; ++j) { Bh[bIdx + j] = hb[j]; Bl[bIdx + j] = lb[j]; }
        }
        __syncthreads();
        bf16x8 ah = __builtin_bit_cast(bf16x8, *(short8*)&Ah[wid * 512 + lane * 8]);
        bf16x8 al = __builtin_bit_cast(bf16x8, *(short8*)&Al[wid * 512 + lane * 8]);
        #pragma unroll
        for (int c = 0; c < 4; ++c) {
            bf16x8 bh = __builtin_bit_cast(bf16x8, *(short8*)&Bh[c * 512 + lane * 8]);
            bf16x8 bl = __builtin_bit_cast(bf16x8, *(short8*)&Bl[c * 512 + lane * 8]);
            acc[c] = __builtin_amdgcn_mfma_f32_16x16x32_bf16(ah, bh, acc[c], 0, 0, 0);
            acc[c] = __builtin_amdgcn_mfma_f32_16x16x32_bf16(al, bh, acc[c], 0, 0, 0);
            acc[c] = __builtin_amdgcn_mfma_f32_16x16x32_bf16(ah, bl, acc[c], 0, 0, 0);
        }
        __syncthreads();
    }
    // epilogue: C/D layout col=lane&15, row=(lane>>4)*4+reg
    int quad = lane >> 4;
    int cl = lane & 15;
    #pragma unroll
    for (int c = 0; c < 4; ++c) {
        #pragma unroll
        for (int r = 0; r < 4; ++r) {
            int row = m0 + wid * 16 + quad * 4 + r;
            if (row < n) h1[(size_t)row * NH + c * 16 + cl] = acc[c][r];
        }
    }
}

// ---------------- agg1: wave/node, coop edge load, batch-8 independent gathers --
__global__ void k_agg1(const float* __restrict__ h1, const float* __restrict__ dinv,
                       const int* __restrict__ rowptr_tot, const int* __restrict__ cnt_tot,
                       const int* __restrict__ esrc, const float* __restrict__ wsrc,
                       const float* __restrict__ b1, float* __restrict__ h1agg, int n) {
    int wave = threadIdx.x >> 6;
    int lane = threadIdx.x & 63;
    int v = blockIdx.x * 4 + wave;
    if (v >= n) return;
    float dv = dinv[v];
    float acc = dv * dv * h1[(size_t)v * NH + lane];
    int beg = rowptr_tot[v];
    int end = beg + cnt_tot[v];
    for (int base = beg; base < end; base += 64) {
        int cnt = end - base;
        if (cnt > 64) cnt = 64;
        int s = 0;
        float w = 0.f;
        if (lane < cnt) {
            s = esrc[base + lane];
            w = wsrc[base + lane] * dv;
        }
        int j = 0;
        for (; j + 8 <= cnt; j += 8) {
            float vals[8], ww[8];
            #pragma unroll
            for (int u = 0; u < 8; ++u) {
                int sj = __shfl(s, j + u);
                ww[u] = __shfl(w, j + u);
                vals[u] = h1[(size_t)sj * NH + lane];
            }
            #pragma unroll
            for (int u = 0; u < 8; ++u) acc = fmaf(ww[u], vals[u], acc);
        }
        if (j < cnt) {
            float vals[8], ww[8];
            #pragma unroll
            for (int u = 0; u < 8; ++u) {
                int idx = j + u;
                int pick = (idx < cnt) ? idx : 0;
                int sj = __shfl(s, pick);
                float wv = __shfl(w, pick);
                ww[u] = (idx < cnt) ? wv : 0.f;
                vals[u] = h1[(size_t)sj * NH + lane];
            }
            #pragma unroll
            for (int u = 0; u < 8; ++u) acc = fmaf(ww[u], vals[u], acc);
        }
    }
    acc += b1[lane];
    h1agg[(size_t)v * NH + lane] = fmaxf(acc, 0.f);
}

// ---------------- GEMM2: g = h1agg @ W2   [n,64]x[64,16] ----------------
__global__ void k_gemm2(const float* __restrict__ h1agg, const float* __restrict__ W2,
                        float* __restrict__ g, int n) {
    __shared__ float W2s[NH * NC];
    {
        int t = threadIdx.x;
        #pragma unroll
        for (int r = 0; r < 4; ++r) W2s[t + r * 256] = W2[t + r * 256];
    }
    __syncthreads();
    int grp = threadIdx.x >> 4;
    int c = threadIdx.x & 15;
    int v = blockIdx.x * 16 + grp;
    if (v >= n) return;
    float acc = 0.f;
    const float* row = &h1agg[(size_t)v * NH];
    #pragma unroll
    for (int k4 = 0; k4 < NH; k4 += 4) {
        float4 h = *(const float4*)&row[k4];
        acc = fmaf(h.x, W2s[(k4 + 0) * NC + c], acc);
        acc = fmaf(h.y, W2s[(k4 + 1) * NC + c], acc);
        acc = fmaf(h.z, W2s[(k4 + 2) * NC + c], acc);
        acc = fmaf(h.w, W2s[(k4 + 3) * NC + c], acc);
    }
    g[(size_t)v * NC + c] = acc;
}

// ---------------- agg2 + bias + log_softmax: 16-lane group/node, batch-8 -------
__global__ void k_agg2(const float* __restrict__ g, const float* __restrict__ dinv,
                       const int* __restrict__ rowptr_tot, const int* __restrict__ cnt_tot,
                       const int* __restrict__ esrc, const float* __restrict__ wsrc,
                       const float* __restrict__ b2, float* __restrict__ out, int n) {
    int grp = threadIdx.x >> 4;
    int lane = threadIdx.x & 15;
    int v = blockIdx.x * 16 + grp;
    if (v >= n) return;
    float dv = dinv[v];
    float acc = dv * dv * g[(size_t)v * NC + lane];
    int beg = rowptr_tot[v];
    int end = beg + cnt_tot[v];
    for (int base = beg; base < end; base += 16) {
        int cnt = end - base;
        if (cnt > 16) cnt = 16;
        int s = 0;
        float w = 0.f;
        if (lane < cnt) {
            s = esrc[base + lane];
            w = wsrc[base + lane] * dv;
        }
        int j = 0;
        for (; j + 8 <= cnt; j += 8) {
            float vals[8], ww[8];
            #pragma unroll
            for (int u = 0; u < 8; ++u) {
                int sj = __shfl(s, j + u, 16);
                ww[u] = __shfl(w, j + u, 16);
                vals[u] = g[(size_t)sj * NC + lane];
            }
            #pragma unroll
            for (int u = 0; u < 8; ++u) acc = fmaf(ww[u], vals[u], acc);
        }
        if (j < cnt) {
            float vals[8], ww[8];
            #pragma unroll
            for (int u = 0; u < 8; ++u) {
                int idx = j + u;
                int pick = (idx < cnt) ? idx : 0;
                int sj = __shfl(s, pick, 16);
                float wv = __shfl(w, pick, 16);
                ww[u] = (idx < cnt) ? wv : 0.f;
                vals[u] = g[(size_t)sj * NC + lane];
            }
            #pragma unroll
            for (int u = 0; u < 8; ++u) acc = fmaf(ww[u], vals[u], acc);
        }
    }
    acc += b2[lane];
    float m = acc;
    #pragma unroll
    for (int mask = 1; mask < 16; mask <<= 1)
        m = fmaxf(m, __shfl_xor(m, mask, 16));
    float ex = __expf(acc - m);
    float ssum = ex;
    #pragma unroll
    for (int mask = 1; mask < 16; mask <<= 1)
        ssum += __shfl_xor(ssum, mask, 16);
    out[(size_t)v * NC + lane] = acc - m - __logf(ssum);
}

extern "C" void kernel_launch(void* const* d_in, const int* in_sizes, int n_in,
                              void* d_out, int out_size, void* d_ws, size_t ws_size,
                              hipStream_t stream) {
    const float* x  = (const float*)d_in[0];
    const int*   ei = (const int*)d_in[1];
    const float* W1 = (const float*)d_in[2];
    const float* b1 = (const float*)d_in[3];
    const float* W2 = (const float*)d_in[4];
    const float* b2 = (const float*)d_in[5];
    float* out = (float*)d_out;

    const int N = in_sizes[0] / NF;
    const int E = in_sizes[1] / 2;
    const int M = NPART * N;
    const int* src = ei;
    const int* dst = ei + E;

    // workspace layout
    char* ws = (char*)d_ws;
    size_t o = 0;
    int*   cnt8       = (int*)(ws + o);   o += (size_t)M * 4;        // 3.2 MB
    int*   cursor8    = (int*)(ws + o);   o += (size_t)M * 4;        // 3.2 MB
    int*   cnt_tot    = (int*)(ws + o);   o += (size_t)N * 4;
    int*   rowptr_tot = (int*)(ws + o);   o += (size_t)N * 4;
    float* dinv       = (float*)(ws + o); o += (size_t)N * 4;
    int*   bsums      = (int*)(ws + o);   o += 4096;
    int*   esrc       = (int*)(ws + o);   o += (size_t)E * 4;        // 6.4 MB
    float* wsrc       = (float*)(ws + o); o += (size_t)E * 4;        // 6.4 MB
    float* h1         = (float*)(ws + o); o += (size_t)N * NH * 4;   // 25.6 MB
    float* h1agg      = (float*)(ws + o); o += (size_t)N * NH * 4;   // 25.6 MB
    float* g          = h1;  // alias: h1 dead after agg1

    hipMemsetAsync(cnt8, 0, (size_t)M * 4, stream);

    int gE  = (E + 255) / 256;
    int gN  = (N + 255) / 256;
    int nbN = (N + 1023) / 1024;

    k_count<<<gE, 256, 0, stream>>>(dst, cnt8, E, N);
    k_dinv<<<gN, 256, 0, stream>>>(cnt8, dinv, cnt_tot, N);
    k_scan1<<<nbN, 1024, 0, stream>>>(cnt_tot, rowptr_tot, bsums, N);
    k_scan2<<<1, 1024, 0, stream>>>(bsums, nbN);
    k_scan3<<<nbN, 1024, 0, stream>>>(rowptr_tot, bsums, N);
    k_cursor<<<gN, 256, 0, stream>>>(cnt8, rowptr_tot, cursor8, N);
    k_fill<<<gE, 256, 0, stream>>>(src, dst, cursor8, esrc, E, N);
    k_wsrc<<<gE, 256, 0, stream>>>(esrc, dinv, wsrc, E);

    k_gemm1<<<(N + 63) / 64, 256, 0, stream>>>(x, W1, h1, N);
    k_agg1<<<(N + 3) / 4, 256, 0, stream>>>(h1, dinv, rowptr_tot, cnt_tot, esrc, wsrc, b1, h1agg, N);
    k_gemm2<<<(N + 15) / 16, 256, 0, stream>>>(h1agg, W2, g, N);
    k_agg2<<<(N + 15) / 16, 0x100, 0, stream>>>(g, dinv, rowptr_tot, cnt_tot, esrc, wsrc, b2, out, N);
}

// Round 5
// 365.941 us; speedup vs baseline: 1.5013x; 1.2831x over previous
//
#include <hip/hip_runtime.h>
#include <hip/hip_bf16.h>
#include <math.h>

#define NF 256
#define NH 64
#define NC 16
#define NBMAX 512      // max buckets (N/256 <= 512 -> N <= 131072)
#define BTILE 8192     // edges per k_bin block

typedef __attribute__((ext_vector_type(8))) __bf16 bf16x8;
typedef __attribute__((ext_vector_type(4))) float f32x4;
typedef __attribute__((ext_vector_type(8))) short short8;

__device__ __forceinline__ unsigned short f2bf(float v) {   // RNE fp32->bf16
    unsigned u = __float_as_uint(v);
    unsigned r = u + 0x7fffu + ((u >> 16) & 1u);
    return (unsigned short)(r >> 16);
}
__device__ __forceinline__ float bf2f(unsigned short s) {
    return __uint_as_float(((unsigned)s) << 16);
}

// ---------------- bucket cursor init: bcur[b] = b*cap ----------------
__global__ void k_binit(int* __restrict__ bcur, int NB, int cap) {
    int b = blockIdx.x * 256 + threadIdx.x;
    if (b < NB) bcur[b] = b * cap;
}

// ---------------- pass 1: bin edges by dst>>8 into bucket regions ----------
// Each (tile,bucket) run is reserved once and written by ONE block -> lines
// assemble in a single XCD's L2 (no cross-XCD write amplification).
__global__ __launch_bounds__(256) void k_bin(const int* __restrict__ src,
                                             const int* __restrict__ dst,
                                             int* __restrict__ bcur,
                                             int2* __restrict__ binned, int E, int NB) {
    __shared__ int histA[NBMAX], histB[NBMAX], gbase[NBMAX];
    int tid = threadIdx.x;
    int e0 = blockIdx.x * BTILE;
    for (int b = tid; b < NB; b += 256) { histA[b] = 0; histB[b] = 0; }
    __syncthreads();
    #pragma unroll
    for (int u = 0; u < BTILE / 256; ++u) {
        int i = e0 + u * 256 + tid;
        if (i < E) atomicAdd(&histA[dst[i] >> 8], 1);
    }
    __syncthreads();
    for (int b = tid; b < NB; b += 256) {
        int c = histA[b];
        gbase[b] = c ? atomicAdd(&bcur[b], c) : 0;
    }
    __syncthreads();
    #pragma unroll
    for (int u = 0; u < BTILE / 256; ++u) {
        int i = e0 + u * 256 + tid;
        if (i < E) {
            int d = dst[i];
            int b = d >> 8;
            int r = atomicAdd(&histB[b], 1);
            binned[gbase[b] + r] = make_int2(src[i], d);
        }
    }
}

// ---------------- pass 2a: per-bucket degree count (dense, LDS-only atomics) ---
__global__ __launch_bounds__(256) void k_bcount(const int2* __restrict__ binned,
                                                const int* __restrict__ bcur,
                                                int* __restrict__ cnt_tot, int cap, int N) {
    __shared__ int h[256];
    int b = blockIdx.x;
    int tid = threadIdx.x;
    h[tid] = 0;
    __syncthreads();
    int base = b * cap;
    int ne = bcur[b] - base;
    for (int i = tid; i < ne; i += 256) atomicAdd(&h[binned[base + i].y & 255], 1);
    __syncthreads();
    int v = (b << 8) + tid;
    if (v < N) cnt_tot[v] = h[tid];
}

// dinv[v] = rsqrt(indeg + 1)
__global__ void k_dinv(const int* __restrict__ cnt_tot, float* __restrict__ dinv, int n) {
    int i = blockIdx.x * 256 + threadIdx.x;
    if (i < n) dinv[i] = rsqrtf((float)(cnt_tot[i] + 1));
}

// ---------------- exclusive scan over N (3 kernels) ----------------
__global__ void k_scan1(const int* __restrict__ cnt, int* __restrict__ rowptr,
                        int* __restrict__ bsums, int M) {
    __shared__ int s[1024];
    int t = threadIdx.x;
    int i = blockIdx.x * 1024 + t;
    int v = (i < M) ? cnt[i] : 0;
    s[t] = v;
    __syncthreads();
    for (int off = 1; off < 1024; off <<= 1) {
        int add = (t >= off) ? s[t - off] : 0;
        __syncthreads();
        s[t] += add;
        __syncthreads();
    }
    if (i < M) rowptr[i] = s[t] - v;
    if (t == 1023) bsums[blockIdx.x] = s[1023];
}

__global__ void k_scan2(int* __restrict__ bsums, int nb) {
    __shared__ int s[1024];
    int t = threadIdx.x;
    int v = (t < nb) ? bsums[t] : 0;
    s[t] = v;
    __syncthreads();
    for (int off = 1; off < 1024; off <<= 1) {
        int add = (t >= off) ? s[t - off] : 0;
        __syncthreads();
        s[t] += add;
        __syncthreads();
    }
    if (t < nb) bsums[t] = s[t] - v;
}

__global__ void k_scan3(int* __restrict__ rowptr, const int* __restrict__ bsums, int M) {
    int i = blockIdx.x * 1024 + threadIdx.x;
    if (i < M) rowptr[i] += bsums[blockIdx.x];
}

// ---------------- pass 2b: per-bucket scatter + wsrc (LDS cursors) ------------
// One block per bucket: esrc writes confined to the bucket's node-major slice
// (~16-20 KB) -> assembles in one L2. wsrc computed over the same slice.
__global__ __launch_bounds__(256) void k_scatter(const int2* __restrict__ binned,
                                                 const int* __restrict__ bcur,
                                                 const int* __restrict__ rowptr_tot,
                                                 const float* __restrict__ dinv,
                                                 int* __restrict__ esrc,
                                                 float* __restrict__ wsrc, int cap, int N) {
    __shared__ int cur[256];
    int b = blockIdx.x;
    int tid = threadIdx.x;
    int node0 = b << 8;
    int v = node0 + tid;
    cur[tid] = (v < N) ? rowptr_tot[v] : 0;
    __syncthreads();
    int base = b * cap;
    int ne = bcur[b] - base;
    for (int i = tid; i < ne; i += 256) {
        int2 e = binned[base + i];
        int pos = atomicAdd(&cur[e.y & 255], 1);
        esrc[pos] = e.x;
    }
    __syncthreads();
    int r0 = rowptr_tot[node0];
    for (int i = r0 + tid; i < r0 + ne; i += 256) wsrc[i] = dinv[esrc[i]];
}

// ---------------- GEMM1 (MFMA bf16 hi/lo split): h1 = x @ W1 -------------------
__global__ __launch_bounds__(256) void k_gemm1(const float* __restrict__ x,
                                               const float* __restrict__ W1,
                                               float* __restrict__ h1, int n) {
    __shared__ __align__(16) unsigned short Ah[2048], Al[2048], Bh[2048], Bl[2048];
    int tid = threadIdx.x;
    int lane = tid & 63;
    int wid = tid >> 6;          // rowgroup 0..3
    int m0 = blockIdx.x * 64;
    f32x4 acc[4] = {{0.f, 0.f, 0.f, 0.f}, {0.f, 0.f, 0.f, 0.f},
                    {0.f, 0.f, 0.f, 0.f}, {0.f, 0.f, 0.f, 0.f}};

    int bcol = tid & 63;
    int bkq = tid >> 6;          // k-quad 0..3
    int bIdx = ((bcol >> 4) * 512) + (((bkq << 4) | (bcol & 15)) * 8);  // shorts

    for (int k0 = 0; k0 < NF; k0 += 32) {
        #pragma unroll
        for (int it = 0; it < 2; ++it) {
            int f = tid + it * 256;
            int m = f >> 3;
            int g = f & 7;
            int node = m0 + m;
            float4 xv = make_float4(0.f, 0.f, 0.f, 0.f);
            if (node < n) xv = *(const float4*)&x[(size_t)node * NF + k0 + g * 4];
            ushort4 hi, lo;
            hi.x = f2bf(xv.x); lo.x = f2bf(xv.x - bf2f(hi.x));
            hi.y = f2bf(xv.y); lo.y = f2bf(xv.y - bf2f(hi.y));
            hi.z = f2bf(xv.z); lo.z = f2bf(xv.z - bf2f(hi.z));
            hi.w = f2bf(xv.w); lo.w = f2bf(xv.w - bf2f(hi.w));
            int aIdx = ((m >> 4) * 512) + ((((g >> 1) << 4) | (m & 15)) * 8) + (g & 1) * 4;
            *(ushort4*)&Ah[aIdx] = hi;
            *(ushort4*)&Al[aIdx] = lo;
        }
        {
            unsigned short hb[8], lb[8];
            #pragma unroll
            for (int j = 0; j < 8; ++j) {
                float w = W1[(size_t)(k0 + bkq * 8 + j) * NH + bcol];
                hb[j] = f2bf(w);
                lb[j] = f2bf(w - bf2f(hb[j]));
            }
            #pragma unroll
            for (int j = 0; j < 8; ++j) { Bh[bIdx + j] = hb[j]; Bl[bIdx + j] = lb[j]; }
        }
        __syncthreads();
        bf16x8 ah = __builtin_bit_cast(bf16x8, *(short8*)&Ah[wid * 512 + lane * 8]);
        bf16x8 al = __builtin_bit_cast(bf16x8, *(short8*)&Al[wid * 512 + lane * 8]);
        #pragma unroll
        for (int c = 0; c < 4; ++c) {
            bf16x8 bh = __builtin_bit_cast(bf16x8, *(short8*)&Bh[c * 512 + lane * 8]);
            bf16x8 bl = __builtin_bit_cast(bf16x8, *(short8*)&Bl[c * 512 + lane * 8]);
            acc[c] = __builtin_amdgcn_mfma_f32_16x16x32_bf16(ah, bh, acc[c], 0, 0, 0);
            acc[c] = __builtin_amdgcn_mfma_f32_16x16x32_bf16(al, bh, acc[c], 0, 0, 0);
            acc[c] = __builtin_amdgcn_mfma_f32_16x16x32_bf16(ah, bl, acc[c], 0, 0, 0);
        }
        __syncthreads();
    }
    int quad = lane >> 4;
    int cl = lane & 15;
    #pragma unroll
    for (int c = 0; c < 4; ++c) {
        #pragma unroll
        for (int r = 0; r < 4; ++r) {
            int row = m0 + wid * 16 + quad * 4 + r;
            if (row < n) h1[(size_t)row * NH + c * 16 + cl] = acc[c][r];
        }
    }
}

// ---------------- agg1: wave/node, coop edge load, batch-8 independent gathers --
__global__ void k_agg1(const float* __restrict__ h1, const float* __restrict__ dinv,
                       const int* __restrict__ rowptr_tot, const int* __restrict__ cnt_tot,
                       const int* __restrict__ esrc, const float* __restrict__ wsrc,
                       const float* __restrict__ b1, float* __restrict__ h1agg, int n) {
    int wave = threadIdx.x >> 6;
    int lane = threadIdx.x & 63;
    int v = blockIdx.x * 4 + wave;
    if (v >= n) return;
    float dv = dinv[v];
    float acc = dv * dv * h1[(size_t)v * NH + lane];
    int beg = rowptr_tot[v];
    int end = beg + cnt_tot[v];
    for (int base = beg; base < end; base += 64) {
        int cnt = end - base;
        if (cnt > 64) cnt = 64;
        int s = 0;
        float w = 0.f;
        if (lane < cnt) {
            s = esrc[base + lane];
            w = wsrc[base + lane] * dv;
        }
        int j = 0;
        for (; j + 8 <= cnt; j += 8) {
            float vals[8], ww[8];
            #pragma unroll
            for (int u = 0; u < 8; ++u) {
                int sj = __shfl(s, j + u);
                ww[u] = __shfl(w, j + u);
                vals[u] = h1[(size_t)sj * NH + lane];
            }
            #pragma unroll
            for (int u = 0; u < 8; ++u) acc = fmaf(ww[u], vals[u], acc);
        }
        if (j < cnt) {
            float vals[8], ww[8];
            #pragma unroll
            for (int u = 0; u < 8; ++u) {
                int idx = j + u;
                int pick = (idx < cnt) ? idx : 0;
                int sj = __shfl(s, pick);
                float wv = __shfl(w, pick);
                ww[u] = (idx < cnt) ? wv : 0.f;
                vals[u] = h1[(size_t)sj * NH + lane];
            }
            #pragma unroll
            for (int u = 0; u < 8; ++u) acc = fmaf(ww[u], vals[u], acc);
        }
    }
    acc += b1[lane];
    h1agg[(size_t)v * NH + lane] = fmaxf(acc, 0.f);
}

// ---------------- GEMM2: g = h1agg @ W2   [n,64]x[64,16] ----------------
__global__ void k_gemm2(const float* __restrict__ h1agg, const float* __restrict__ W2,
                        float* __restrict__ g, int n) {
    __shared__ float W2s[NH * NC];
    {
        int t = threadIdx.x;
        #pragma unroll
        for (int r = 0; r < 4; ++r) W2s[t + r * 256] = W2[t + r * 256];
    }
    __syncthreads();
    int grp = threadIdx.x >> 4;
    int c = threadIdx.x & 15;
    int v = blockIdx.x * 16 + grp;
    if (v >= n) return;
    float acc = 0.f;
    const float* row = &h1agg[(size_t)v * NH];
    #pragma unroll
    for (int k4 = 0; k4 < NH; k4 += 4) {
        float4 h = *(const float4*)&row[k4];
        acc = fmaf(h.x, W2s[(k4 + 0) * NC + c], acc);
        acc = fmaf(h.y, W2s[(k4 + 1) * NC + c], acc);
        acc = fmaf(h.z, W2s[(k4 + 2) * NC + c], acc);
        acc = fmaf(h.w, W2s[(k4 + 3) * NC + c], acc);
    }
    g[(size_t)v * NC + c] = acc;
}

// ---------------- agg2 + bias + log_softmax: 16-lane group/node, batch-8 -------
__global__ void k_agg2(const float* __restrict__ g, const float* __restrict__ dinv,
                       const int* __restrict__ rowptr_tot, const int* __restrict__ cnt_tot,
                       const int* __restrict__ esrc, const float* __restrict__ wsrc,
                       const float* __restrict__ b2, float* __restrict__ out, int n) {
    int grp = threadIdx.x >> 4;
    int lane = threadIdx.x & 15;
    int v = blockIdx.x * 16 + grp;
    if (v >= n) return;
    float dv = dinv[v];
    float acc = dv * dv * g[(size_t)v * NC + lane];
    int beg = rowptr_tot[v];
    int end = beg + cnt_tot[v];
    for (int base = beg; base < end; base += 16) {
        int cnt = end - base;
        if (cnt > 16) cnt = 16;
        int s = 0;
        float w = 0.f;
        if (lane < cnt) {
            s = esrc[base + lane];
            w = wsrc[base + lane] * dv;
        }
        int j = 0;
        for (; j + 8 <= cnt; j += 8) {
            float vals[8], ww[8];
            #pragma unroll
            for (int u = 0; u < 8; ++u) {
                int sj = __shfl(s, j + u, 16);
                ww[u] = __shfl(w, j + u, 16);
                vals[u] = g[(size_t)sj * NC + lane];
            }
            #pragma unroll
            for (int u = 0; u < 8; ++u) acc = fmaf(ww[u], vals[u], acc);
        }
        if (j < cnt) {
            float vals[8], ww[8];
            #pragma unroll
            for (int u = 0; u < 8; ++u) {
                int idx = j + u;
                int pick = (idx < cnt) ? idx : 0;
                int sj = __shfl(s, pick, 16);
                float wv = __shfl(w, pick, 16);
                ww[u] = (idx < cnt) ? wv : 0.f;
                vals[u] = g[(size_t)sj * NC + lane];
            }
            #pragma unroll
            for (int u = 0; u < 8; ++u) acc = fmaf(ww[u], vals[u], acc);
        }
    }
    acc += b2[lane];
    float m = acc;
    #pragma unroll
    for (int mask = 1; mask < 16; mask <<= 1)
        m = fmaxf(m, __shfl_xor(m, mask, 16));
    float ex = __expf(acc - m);
    float ssum = ex;
    #pragma unroll
    for (int mask = 1; mask < 16; mask <<= 1)
        ssum += __shfl_xor(ssum, mask, 16);
    out[(size_t)v * NC + lane] = acc - m - __logf(ssum);
}

extern "C" void kernel_launch(void* const* d_in, const int* in_sizes, int n_in,
                              void* d_out, int out_size, void* d_ws, size_t ws_size,
                              hipStream_t stream) {
    const float* x  = (const float*)d_in[0];
    const int*   ei = (const int*)d_in[1];
    const float* W1 = (const float*)d_in[2];
    const float* b1 = (const float*)d_in[3];
    const float* W2 = (const float*)d_in[4];
    const float* b2 = (const float*)d_in[5];
    float* out = (float*)d_out;

    const int N = in_sizes[0] / NF;
    const int E = in_sizes[1] / 2;
    const int* src = ei;
    const int* dst = ei + E;

    const int NB  = (N + 255) >> 8;                       // buckets of 256 nodes
    const int per = (E + NB - 1) / NB;
    const int cap = (per + (per >> 2) + 511) & ~511;      // +25% slack, 512-aligned

    // workspace layout
    char* ws = (char*)d_ws;
    size_t o = 0;
    int*   cnt_tot    = (int*)(ws + o);   o += (size_t)N * 4;
    int*   rowptr_tot = (int*)(ws + o);   o += (size_t)N * 4;
    float* dinv       = (float*)(ws + o); o += (size_t)N * 4;
    int*   bsums      = (int*)(ws + o);   o += 4096;
    int*   bcur       = (int*)(ws + o);   o += (size_t)NBMAX * 4;
    int*   esrc       = (int*)(ws + o);   o += (size_t)E * 4;        // 6.4 MB
    float* wsrc       = (float*)(ws + o); o += (size_t)E * 4;        // 6.4 MB
    float* h1         = (float*)(ws + o); o += (size_t)N * NH * 4;   // 25.6 MB
    float* h1agg      = (float*)(ws + o); o += (size_t)N * NH * 4;   // 25.6 MB
    float* g          = h1;              // alias: h1 dead after agg1
    int2*  binned     = (int2*)h1agg;    // alias: binned dead before agg1 writes h1agg
                                         // (NB*cap*8 = ~16 MB <= 25.6 MB)

    int gN  = (N + 255) / 256;
    int nbN = (N + 1023) / 1024;
    int nbin = (E + BTILE - 1) / BTILE;

    k_binit<<<(NB + 255) / 256, 256, 0, stream>>>(bcur, NB, cap);
    k_bin<<<nbin, 256, 0, stream>>>(src, dst, bcur, binned, E, NB);
    k_bcount<<<NB, 256, 0, stream>>>(binned, bcur, cnt_tot, cap, N);
    k_dinv<<<gN, 256, 0, stream>>>(cnt_tot, dinv, N);
    k_scan1<<<nbN, 1024, 0, stream>>>(cnt_tot, rowptr_tot, bsums, N);
    k_scan2<<<1, 1024, 0, stream>>>(bsums, nbN);
    k_scan3<<<nbN, 1024, 0, stream>>>(rowptr_tot, bsums, N);
    k_scatter<<<NB, 256, 0, stream>>>(binned, bcur, rowptr_tot, dinv, esrc, wsrc, cap, N);

    k_gemm1<<<(N + 63) / 64, 256, 0, stream>>>(x, W1, h1, N);
    k_agg1<<<(N + 3) / 4, 256, 0, stream>>>(h1, dinv, rowptr_tot, cnt_tot, esrc, wsrc, b1, h1agg, N);
    k_gemm2<<<(N + 15) / 16, 256, 0, stream>>>(h1agg, W2, g, N);
    k_agg2<<<(N + 15) / 16, 256, 0, stream>>>(g, dinv, rowptr_tot, cnt_tot, esrc, wsrc, b2, out, N);
}

// Round 9
// 361.418 us; speedup vs baseline: 1.5201x; 1.0125x over previous
//
#include <hip/hip_runtime.h>
#include <hip/hip_bf16.h>
#include <math.h>

#define NF 256
#define NH 64
#define NC 16
#define NBMAX 512      // max buckets (N/256 <= 512 -> N <= 131072)
#define BTILE 8192     // edges per k_bin block

typedef __attribute__((ext_vector_type(8))) __bf16 bf16x8;
typedef __attribute__((ext_vector_type(4))) float f32x4;
typedef __attribute__((ext_vector_type(8))) short short8;

__device__ __forceinline__ unsigned short f2bf(float v) {   // RNE fp32->bf16
    unsigned u = __float_as_uint(v);
    unsigned r = u + 0x7fffu + ((u >> 16) & 1u);
    return (unsigned short)(r >> 16);
}
__device__ __forceinline__ float bf2f(unsigned short s) {
    return __uint_as_float(((unsigned)s) << 16);
}

// ---------------- bucket cursor init: bcur[b] = b*cap ----------------
__global__ void k_binit(int* __restrict__ bcur, int NB, int cap) {
    int b = blockIdx.x * 256 + threadIdx.x;
    if (b < NB) bcur[b] = b * cap;
}

// ---------------- pass 1: bin edges by dst>>8 into bucket regions ----------
// packed entry: src | (dst&255)<<24   (requires N < 2^24)
__global__ __launch_bounds__(256) void k_bin(const int* __restrict__ src,
                                             const int* __restrict__ dst,
                                             int* __restrict__ bcur,
                                             int* __restrict__ binned, int E, int NB) {
    __shared__ int histA[NBMAX], histB[NBMAX], gbase[NBMAX];
    int tid = threadIdx.x;
    int e0 = blockIdx.x * BTILE;
    for (int b = tid; b < NB; b += 256) { histA[b] = 0; histB[b] = 0; }
    __syncthreads();
    #pragma unroll
    for (int u = 0; u < BTILE / 256; ++u) {
        int i = e0 + u * 256 + tid;
        if (i < E) atomicAdd(&histA[dst[i] >> 8], 1);
    }
    __syncthreads();
    for (int b = tid; b < NB; b += 256) {
        int c = histA[b];
        gbase[b] = c ? atomicAdd(&bcur[b], c) : 0;
    }
    __syncthreads();
    #pragma unroll
    for (int u = 0; u < BTILE / 256; ++u) {
        int i = e0 + u * 256 + tid;
        if (i < E) {
            int d = dst[i];
            int b = d >> 8;
            int r = atomicAdd(&histB[b], 1);
            binned[gbase[b] + r] = src[i] | ((d & 255) << 24);
        }
    }
}

// ---------------- pass 2a: per-bucket degree count (LDS-only atomics) ---------
__global__ __launch_bounds__(256) void k_bcount(const int* __restrict__ binned,
                                                const int* __restrict__ bcur,
                                                int* __restrict__ cnt_tot, int cap, int N) {
    __shared__ int h[256];
    int b = blockIdx.x;
    int tid = threadIdx.x;
    h[tid] = 0;
    __syncthreads();
    int base = b * cap;
    int ne = bcur[b] - base;
    for (int i = tid; i < ne; i += 256)
        atomicAdd(&h[(binned[base + i] >> 24) & 255], 1);
    __syncthreads();
    int v = (b << 8) + tid;
    if (v < N) cnt_tot[v] = h[tid];
}

// dinv[v] = rsqrt(indeg + 1)
__global__ void k_dinv(const int* __restrict__ cnt_tot, float* __restrict__ dinv, int n) {
    int i = blockIdx.x * 256 + threadIdx.x;
    if (i < n) dinv[i] = rsqrtf((float)(cnt_tot[i] + 1));
}

// ---------------- exclusive scan over N (3 kernels) ----------------
__global__ void k_scan1(const int* __restrict__ cnt, int* __restrict__ rowptr,
                        int* __restrict__ bsums, int M) {
    __shared__ int s[1024];
    int t = threadIdx.x;
    int i = blockIdx.x * 1024 + t;
    int v = (i < M) ? cnt[i] : 0;
    s[t] = v;
    __syncthreads();
    for (int off = 1; off < 1024; off <<= 1) {
        int add = (t >= off) ? s[t - off] : 0;
        __syncthreads();
        s[t] += add;
        __syncthreads();
    }
    if (i < M) rowptr[i] = s[t] - v;
    if (t == 1023) bsums[blockIdx.x] = s[1023];
}

__global__ void k_scan2(int* __restrict__ bsums, int nb) {
    __shared__ int s[1024];
    int t = threadIdx.x;
    int v = (t < nb) ? bsums[t] : 0;
    s[t] = v;
    __syncthreads();
    for (int off = 1; off < 1024; off <<= 1) {
        int add = (t >= off) ? s[t - off] : 0;
        __syncthreads();
        s[t] += add;
        __syncthreads();
    }
    if (t < nb) bsums[t] = s[t] - v;
}

__global__ void k_scan3(int* __restrict__ rowptr, const int* __restrict__ bsums, int M) {
    int i = blockIdx.x * 1024 + threadIdx.x;
    if (i < M) rowptr[i] += bsums[blockIdx.x];
}

// ---------------- pass 2b: per-bucket scatter + wsrc (LDS cursors) ------------
__global__ __launch_bounds__(256) void k_scatter(const int* __restrict__ binned,
                                                 const int* __restrict__ bcur,
                                                 const int* __restrict__ rowptr_tot,
                                                 const float* __restrict__ dinv,
                                                 int* __restrict__ esrc,
                                                 float* __restrict__ wsrc, int cap, int N) {
    __shared__ int cur[256];
    int b = blockIdx.x;
    int tid = threadIdx.x;
    int node0 = b << 8;
    int v = node0 + tid;
    cur[tid] = (v < N) ? rowptr_tot[v] : 0;
    __syncthreads();
    int base = b * cap;
    int ne = bcur[b] - base;
    for (int i = tid; i < ne; i += 256) {
        int pk = binned[base + i];
        int pos = atomicAdd(&cur[(pk >> 24) & 255], 1);
        esrc[pos] = pk & 0x00FFFFFF;
    }
    __syncthreads();
    int r0 = rowptr_tot[node0];
    for (int i = r0 + tid; i < r0 + ne; i += 256) wsrc[i] = dinv[esrc[i]];
}

// ---------------- GEMM1 (MFMA bf16 hi/lo split): h1(fp32) = x @ W1 -------------
__global__ __launch_bounds__(256) void k_gemm1(const float* __restrict__ x,
                                               const float* __restrict__ W1,
                                               float* __restrict__ h1, int n) {
    __shared__ __align__(16) unsigned short Ah[2048], Al[2048], Bh[2048], Bl[2048];
    int tid = threadIdx.x;
    int lane = tid & 63;
    int wid = tid >> 6;          // rowgroup 0..3
    int m0 = blockIdx.x * 64;
    f32x4 acc[4] = {{0.f, 0.f, 0.f, 0.f}, {0.f, 0.f, 0.f, 0.f},
                    {0.f, 0.f, 0.f, 0.f}, {0.f, 0.f, 0.f, 0.f}};

    int bcol = tid & 63;
    int bkq = tid >> 6;          // k-quad 0..3
    int bIdx = ((bcol >> 4) * 512) + (((bkq << 4) | (bcol & 15)) * 8);  // shorts

    for (int k0 = 0; k0 < NF; k0 += 32) {
        #pragma unroll
        for (int it = 0; it < 2; ++it) {
            int f = tid + it * 256;
            int m = f >> 3;
            int g = f & 7;
            int node = m0 + m;
            float4 xv = make_float4(0.f, 0.f, 0.f, 0.f);
            if (node < n) xv = *(const float4*)&x[(size_t)node * NF + k0 + g * 4];
            ushort4 hi, lo;
            hi.x = f2bf(xv.x); lo.x = f2bf(xv.x - bf2f(hi.x));
            hi.y = f2bf(xv.y); lo.y = f2bf(xv.y - bf2f(hi.y));
            hi.z = f2bf(xv.z); lo.z = f2bf(xv.z - bf2f(hi.z));
            hi.w = f2bf(xv.w); lo.w = f2bf(xv.w - bf2f(hi.w));
            int aIdx = ((m >> 4) * 512) + ((((g >> 1) << 4) | (m & 15)) * 8) + (g & 1) * 4;
            *(ushort4*)&Ah[aIdx] = hi;
            *(ushort4*)&Al[aIdx] = lo;
        }
        {
            unsigned short hb[8], lb[8];
            #pragma unroll
            for (int j = 0; j < 8; ++j) {
                float w = W1[(size_t)(k0 + bkq * 8 + j) * NH + bcol];
                hb[j] = f2bf(w);
                lb[j] = f2bf(w - bf2f(hb[j]));
            }
            #pragma unroll
            for (int j = 0; j < 8; ++j) { Bh[bIdx + j] = hb[j]; Bl[bIdx + j] = lb[j]; }
        }
        __syncthreads();
        bf16x8 ah = __builtin_bit_cast(bf16x8, *(short8*)&Ah[wid * 512 + lane * 8]);
        bf16x8 al = __builtin_bit_cast(bf16x8, *(short8*)&Al[wid * 512 + lane * 8]);
        #pragma unroll
        for (int c = 0; c < 4; ++c) {
            bf16x8 bh = __builtin_bit_cast(bf16x8, *(short8*)&Bh[c * 512 + lane * 8]);
            bf16x8 bl = __builtin_bit_cast(bf16x8, *(short8*)&Bl[c * 512 + lane * 8]);
            acc[c] = __builtin_amdgcn_mfma_f32_16x16x32_bf16(ah, bh, acc[c], 0, 0, 0);
            acc[c] = __builtin_amdgcn_mfma_f32_16x16x32_bf16(al, bh, acc[c], 0, 0, 0);
            acc[c] = __builtin_amdgcn_mfma_f32_16x16x32_bf16(ah, bl, acc[c], 0, 0, 0);
        }
        __syncthreads();
    }
    int quad = lane >> 4;
    int cl = lane & 15;
    #pragma unroll
    for (int c = 0; c < 4; ++c) {
        #pragma unroll
        for (int r = 0; r < 4; ++r) {
            int row = m0 + wid * 16 + quad * 4 + r;
            if (row < n) h1[(size_t)row * NH + c * 16 + cl] = acc[c][r];
        }
    }
}

// ---------------- agg1: wave/node, float2 gathers, CONVERGENT pair-split ------
// lanes 0-31 sum even-indexed neighbors, 32-63 odd; lane owns feature pair
// (2*fl, 2*fl+1). Both halves run IDENTICAL trip counts (npair = ceil(cnt/2));
// the odd half's phantom element indexes lane==cnt which holds s=0,w=0 -> adds
// exactly 0. Tail is padded to 8 with clamped index + zeroed weight. No __shfl
// ever executes in half-divergent control flow (the R6-R8 bug).
__global__ void k_agg1(const float2* __restrict__ h1, const float* __restrict__ dinv,
                       const int* __restrict__ rowptr_tot, const int* __restrict__ cnt_tot,
                       const int* __restrict__ esrc, const float* __restrict__ wsrc,
                       const float* __restrict__ b1, float* __restrict__ h1agg, int n) {
    int wave = threadIdx.x >> 6;
    int lane = threadIdx.x & 63;
    int v = blockIdx.x * 4 + wave;
    if (v >= n) return;
    int half = lane >> 5;
    int fl = lane & 31;
    float dv = dinv[v];
    float sw = half ? 0.f : dv * dv;
    float2 up = h1[(size_t)v * 32 + fl];
    float2 acc;
    acc.x = sw * up.x;
    acc.y = sw * up.y;
    int beg = rowptr_tot[v];
    int end = beg + cnt_tot[v];
    for (int base = beg; base < end; base += 64) {
        int cnt = end - base;
        if (cnt > 64) cnt = 64;
        int s = 0;
        float w = 0.f;
        if (lane < cnt) {
            s = esrc[base + lane];
            w = wsrc[base + lane] * dv;
        }
        int npair = (cnt + 1) >> 1;   // UNIFORM across halves (convergent)
        int j = 0;
        for (; j + 8 <= npair; j += 8) {
            float2 pv[8];
            float ww[8];
            #pragma unroll
            for (int u = 0; u < 8; ++u) {
                int idx = ((j + u) << 1) | half;   // may equal cnt (odd cnt, half=1): lane cnt has w=0
                int sj = __shfl(s, idx);
                ww[u] = __shfl(w, idx);
                pv[u] = h1[(size_t)sj * 32 + fl];
            }
            #pragma unroll
            for (int u = 0; u < 8; ++u) {
                acc.x = fmaf(ww[u], pv[u].x, acc.x);
                acc.y = fmaf(ww[u], pv[u].y, acc.y);
            }
        }
        if (j < npair) {   // convergent padded tail (all lanes, zeroed weights)
            float2 pv[8];
            float ww[8];
            #pragma unroll
            for (int u = 0; u < 8; ++u) {
                int jj = j + u;
                int idx = (jj << 1) | half;
                int pick = (jj < npair) ? idx : 0;
                int sj = __shfl(s, pick);
                float wv = __shfl(w, pick);
                ww[u] = (jj < npair) ? wv : 0.f;
                pv[u] = h1[(size_t)sj * 32 + fl];
            }
            #pragma unroll
            for (int u = 0; u < 8; ++u) {
                acc.x = fmaf(ww[u], pv[u].x, acc.x);
                acc.y = fmaf(ww[u], pv[u].y, acc.y);
            }
        }
    }
    acc.x += __shfl(acc.x, fl + 32);
    acc.y += __shfl(acc.y, fl + 32);
    if (half == 0) {
        float2 bb = *(const float2*)&b1[2 * fl];
        float2 o;
        o.x = fmaxf(acc.x + bb.x, 0.f);
        o.y = fmaxf(acc.y + bb.y, 0.f);
        *(float2*)&h1agg[(size_t)v * NH + 2 * fl] = o;
    }
}

// ---------------- GEMM2: g = h1agg @ W2   [n,64]x[64,16] ----------------
__global__ void k_gemm2(const float* __restrict__ h1agg, const float* __restrict__ W2,
                        float* __restrict__ g, int n) {
    __shared__ float W2s[NH * NC];
    {
        int t = threadIdx.x;
        #pragma unroll
        for (int r = 0; r < 4; ++r) W2s[t + r * 256] = W2[t + r * 256];
    }
    __syncthreads();
    int grp = threadIdx.x >> 4;
    int c = threadIdx.x & 15;
    int v = blockIdx.x * 16 + grp;
    if (v >= n) return;
    float acc = 0.f;
    const float* row = &h1agg[(size_t)v * NH];
    #pragma unroll
    for (int k4 = 0; k4 < NH; k4 += 4) {
        float4 h = *(const float4*)&row[k4];
        acc = fmaf(h.x, W2s[(k4 + 0) * NC + c], acc);
        acc = fmaf(h.y, W2s[(k4 + 1) * NC + c], acc);
        acc = fmaf(h.z, W2s[(k4 + 2) * NC + c], acc);
        acc = fmaf(h.w, W2s[(k4 + 3) * NC + c], acc);
    }
    g[(size_t)v * NC + c] = acc;
}

// ---------------- agg2 + bias + log_softmax: 16-lane group/node, batch-8 -------
__global__ void k_agg2(const float* __restrict__ g, const float* __restrict__ dinv,
                       const int* __restrict__ rowptr_tot, const int* __restrict__ cnt_tot,
                       const int* __restrict__ esrc, const float* __restrict__ wsrc,
                       const float* __restrict__ b2, float* __restrict__ out, int n) {
    int grp = threadIdx.x >> 4;
    int lane = threadIdx.x & 15;
    int v = blockIdx.x * 16 + grp;
    if (v >= n) return;
    float dv = dinv[v];
    float acc = dv * dv * g[(size_t)v * NC + lane];
    int beg = rowptr_tot[v];
    int end = beg + cnt_tot[v];
    for (int base = beg; base < end; base += 16) {
        int cnt = end - base;
        if (cnt > 16) cnt = 16;
        int s = 0;
        float w = 0.f;
        if (lane < cnt) {
            s = esrc[base + lane];
            w = wsrc[base + lane] * dv;
        }
        int j = 0;
        for (; j + 8 <= cnt; j += 8) {
            float vals[8], ww[8];
            #pragma unroll
            for (int u = 0; u < 8; ++u) {
                int sj = __shfl(s, j + u, 16);
                ww[u] = __shfl(w, j + u, 16);
                vals[u] = g[(size_t)sj * NC + lane];
            }
            #pragma unroll
            for (int u = 0; u < 8; ++u) acc = fmaf(ww[u], vals[u], acc);
        }
        if (j < cnt) {
            float vals[8], ww[8];
            #pragma unroll
            for (int u = 0; u < 8; ++u) {
                int idx = j + u;
                int pick = (idx < cnt) ? idx : 0;
                int sj = __shfl(s, pick, 16);
                float wv = __shfl(w, pick, 16);
                ww[u] = (idx < cnt) ? wv : 0.f;
                vals[u] = g[(size_t)sj * NC + lane];
            }
            #pragma unroll
            for (int u = 0; u < 8; ++u) acc = fmaf(ww[u], vals[u], acc);
        }
    }
    acc += b2[lane];
    float m = acc;
    #pragma unroll
    for (int mask = 1; mask < 16; mask <<= 1)
        m = fmaxf(m, __shfl_xor(m, mask, 16));
    float ex = __expf(acc - m);
    float ssum = ex;
    #pragma unroll
    for (int mask = 1; mask < 16; mask <<= 1)
        ssum += __shfl_xor(ssum, mask, 16);
    out[(size_t)v * NC + lane] = acc - m - __logf(ssum);
}

extern "C" void kernel_launch(void* const* d_in, const int* in_sizes, int n_in,
                              void* d_out, int out_size, void* d_ws, size_t ws_size,
                              hipStream_t stream) {
    const float* x  = (const float*)d_in[0];
    const int*   ei = (const int*)d_in[1];
    const float* W1 = (const float*)d_in[2];
    const float* b1 = (const float*)d_in[3];
    const float* W2 = (const float*)d_in[4];
    const float* b2 = (const float*)d_in[5];
    float* out = (float*)d_out;

    const int N = in_sizes[0] / NF;
    const int E = in_sizes[1] / 2;
    const int* src = ei;
    const int* dst = ei + E;

    const int NB  = (N + 255) >> 8;                       // buckets of 256 nodes
    const int per = (E + NB - 1) / NB;
    const int cap = (per + (per >> 2) + 511) & ~511;      // +25% slack, 512-aligned

    // workspace layout
    char* ws = (char*)d_ws;
    size_t o = 0;
    int*   cnt_tot    = (int*)(ws + o);   o += (size_t)N * 4;
    int*   rowptr_tot = (int*)(ws + o);   o += (size_t)N * 4;
    float* dinv       = (float*)(ws + o); o += (size_t)N * 4;
    int*   bsums      = (int*)(ws + o);   o += 4096;
    int*   bcur       = (int*)(ws + o);   o += (size_t)NBMAX * 4;
    int*   esrc       = (int*)(ws + o);   o += (size_t)E * 4;          // 6.4 MB
    float* wsrc       = (float*)(ws + o); o += (size_t)E * 4;          // 6.4 MB
    float* h1         = (float*)(ws + o); o += (size_t)N * NH * 4;     // 25.6 MB fp32
    float* h1agg      = (float*)(ws + o); o += (size_t)N * NH * 4;     // 25.6 MB
    float* g          = h1;              // alias: h1 dead after agg1
    int*   binned     = (int*)h1agg;     // alias: binned dead before agg1 writes h1agg
                                         // (NB*cap*4 ~ 8.8 MB <= 25.6 MB)

    int gN  = (N + 255) / 256;
    int nbN = (N + 1023) / 1024;
    int nbin = (E + BTILE - 1) / BTILE;

    k_binit<<<(NB + 255) / 256, 256, 0, stream>>>(bcur, NB, cap);
    k_bin<<<nbin, 256, 0, stream>>>(src, dst, bcur, binned, E, NB);
    k_bcount<<<NB, 256, 0, stream>>>(binned, bcur, cnt_tot, cap, N);
    k_dinv<<<gN, 256, 0, stream>>>(cnt_tot, dinv, N);
    k_scan1<<<nbN, 1024, 0, stream>>>(cnt_tot, rowptr_tot, bsums, N);
    k_scan2<<<1, 1024, 0, stream>>>(bsums, nbN);
    k_scan3<<<nbN, 1024, 0, stream>>>(rowptr_tot, bsums, N);
    k_scatter<<<NB, 256, 0, stream>>>(binned, bcur, rowptr_tot, dinv, esrc, wsrc, cap, N);

    k_gemm1<<<(N + 63) / 64, 256, 0, stream>>>(x, W1, h1, N);
    k_agg1<<<(N + 3) / 4, 256, 0, stream>>>((const float2*)h1, dinv, rowptr_tot, cnt_tot,
                                            esrc, wsrc, b1, h1agg, N);
    k_gemm2<<<(N + 15) / 16, 256, 0, stream>>>(h1agg, W2, g, N);
    k_agg2<<<(N + 15) / 16, 256, 0, stream>>>(g, dinv, rowptr_tot, cnt_tot, esrc, wsrc, b2, out, N);
}

// Round 10
// 339.435 us; speedup vs baseline: 1.6185x; 1.0648x over previous
//
#include <hip/hip_runtime.h>
#include <hip/hip_bf16.h>
#include <hip/hip_fp16.h>
#include <math.h>

#define NF 256
#define NH 64
#define NC 16
#define NBMAX 512      // max buckets (N/256 <= 512 -> N <= 131072)
#define BTILE 8192     // edges per k_bin block

typedef __attribute__((ext_vector_type(8))) __bf16 bf16x8;
typedef __attribute__((ext_vector_type(4))) float f32x4;
typedef __attribute__((ext_vector_type(8))) short short8;

__device__ __forceinline__ unsigned short f2bf(float v) {   // RNE fp32->bf16
    unsigned u = __float_as_uint(v);
    unsigned r = u + 0x7fffu + ((u >> 16) & 1u);
    return (unsigned short)(r >> 16);
}
__device__ __forceinline__ float bf2f(unsigned short s) {
    return __uint_as_float(((unsigned)s) << 16);
}

// ---------------- bucket cursor init: bcur[b] = b*cap ----------------
__global__ void k_binit(int* __restrict__ bcur, int NB, int cap) {
    int b = blockIdx.x * 256 + threadIdx.x;
    if (b < NB) bcur[b] = b * cap;
}

// ---------------- pass 1: bin edges by dst>>8 into bucket regions ----------
// packed entry: src | (dst&255)<<24   (requires N < 2^24)
__global__ __launch_bounds__(256) void k_bin(const int* __restrict__ src,
                                             const int* __restrict__ dst,
                                             int* __restrict__ bcur,
                                             int* __restrict__ binned, int E, int NB) {
    __shared__ int histA[NBMAX], histB[NBMAX], gbase[NBMAX];
    int tid = threadIdx.x;
    int e0 = blockIdx.x * BTILE;
    for (int b = tid; b < NB; b += 256) { histA[b] = 0; histB[b] = 0; }
    __syncthreads();
    #pragma unroll
    for (int u = 0; u < BTILE / 256; ++u) {
        int i = e0 + u * 256 + tid;
        if (i < E) atomicAdd(&histA[dst[i] >> 8], 1);
    }
    __syncthreads();
    for (int b = tid; b < NB; b += 256) {
        int c = histA[b];
        gbase[b] = c ? atomicAdd(&bcur[b], c) : 0;
    }
    __syncthreads();
    #pragma unroll
    for (int u = 0; u < BTILE / 256; ++u) {
        int i = e0 + u * 256 + tid;
        if (i < E) {
            int d = dst[i];
            int b = d >> 8;
            int r = atomicAdd(&histB[b], 1);
            binned[gbase[b] + r] = src[i] | ((d & 255) << 24);
        }
    }
}

// ---------------- pass 2a: per-bucket degree count (LDS-only atomics) ---------
__global__ __launch_bounds__(256) void k_bcount(const int* __restrict__ binned,
                                                const int* __restrict__ bcur,
                                                int* __restrict__ cnt_tot, int cap, int N) {
    __shared__ int h[256];
    int b = blockIdx.x;
    int tid = threadIdx.x;
    h[tid] = 0;
    __syncthreads();
    int base = b * cap;
    int ne = bcur[b] - base;
    for (int i = tid; i < ne; i += 256)
        atomicAdd(&h[(binned[base + i] >> 24) & 255], 1);
    __syncthreads();
    int v = (b << 8) + tid;
    if (v < N) cnt_tot[v] = h[tid];
}

// dinv[v] = rsqrt(indeg + 1)
__global__ void k_dinv(const int* __restrict__ cnt_tot, float* __restrict__ dinv, int n) {
    int i = blockIdx.x * 256 + threadIdx.x;
    if (i < n) dinv[i] = rsqrtf((float)(cnt_tot[i] + 1));
}

// ---------------- exclusive scan over N (3 kernels) ----------------
__global__ void k_scan1(const int* __restrict__ cnt, int* __restrict__ rowptr,
                        int* __restrict__ bsums, int M) {
    __shared__ int s[1024];
    int t = threadIdx.x;
    int i = blockIdx.x * 1024 + t;
    int v = (i < M) ? cnt[i] : 0;
    s[t] = v;
    __syncthreads();
    for (int off = 1; off < 1024; off <<= 1) {
        int add = (t >= off) ? s[t - off] : 0;
        __syncthreads();
        s[t] += add;
        __syncthreads();
    }
    if (i < M) rowptr[i] = s[t] - v;
    if (t == 1023) bsums[blockIdx.x] = s[1023];
}

__global__ void k_scan2(int* __restrict__ bsums, int nb) {
    __shared__ int s[1024];
    int t = threadIdx.x;
    int v = (t < nb) ? bsums[t] : 0;
    s[t] = v;
    __syncthreads();
    for (int off = 1; off < 1024; off <<= 1) {
        int add = (t >= off) ? s[t - off] : 0;
        __syncthreads();
        s[t] += add;
        __syncthreads();
    }
    if (t < nb) bsums[t] = s[t] - v;
}

__global__ void k_scan3(int* __restrict__ rowptr, const int* __restrict__ bsums, int M) {
    int i = blockIdx.x * 1024 + threadIdx.x;
    if (i < M) rowptr[i] += bsums[blockIdx.x];
}

// ---------------- pass 2b: per-bucket scatter + wsrc (LDS cursors) ------------
__global__ __launch_bounds__(256) void k_scatter(const int* __restrict__ binned,
                                                 const int* __restrict__ bcur,
                                                 const int* __restrict__ rowptr_tot,
                                                 const float* __restrict__ dinv,
                                                 int* __restrict__ esrc,
                                                 float* __restrict__ wsrc, int cap, int N) {
    __shared__ int cur[256];
    int b = blockIdx.x;
    int tid = threadIdx.x;
    int node0 = b << 8;
    int v = node0 + tid;
    cur[tid] = (v < N) ? rowptr_tot[v] : 0;
    __syncthreads();
    int base = b * cap;
    int ne = bcur[b] - base;
    for (int i = tid; i < ne; i += 256) {
        int pk = binned[base + i];
        int pos = atomicAdd(&cur[(pk >> 24) & 255], 1);
        esrc[pos] = pk & 0x00FFFFFF;
    }
    __syncthreads();
    int r0 = rowptr_tot[node0];
    for (int i = r0 + tid; i < r0 + ne; i += 256) wsrc[i] = dinv[esrc[i]];
}

// ---------------- GEMM1 (MFMA bf16 hi/lo split): h1(fp16) = x @ W1 -------------
__global__ __launch_bounds__(256) void k_gemm1(const float* __restrict__ x,
                                               const float* __restrict__ W1,
                                               __half* __restrict__ h1, int n) {
    __shared__ __align__(16) unsigned short Ah[2048], Al[2048], Bh[2048], Bl[2048];
    int tid = threadIdx.x;
    int lane = tid & 63;
    int wid = tid >> 6;          // rowgroup 0..3
    int m0 = blockIdx.x * 64;
    f32x4 acc[4] = {{0.f, 0.f, 0.f, 0.f}, {0.f, 0.f, 0.f, 0.f},
                    {0.f, 0.f, 0.f, 0.f}, {0.f, 0.f, 0.f, 0.f}};

    int bcol = tid & 63;
    int bkq = tid >> 6;          // k-quad 0..3
    int bIdx = ((bcol >> 4) * 512) + (((bkq << 4) | (bcol & 15)) * 8);  // shorts

    for (int k0 = 0; k0 < NF; k0 += 32) {
        #pragma unroll
        for (int it = 0; it < 2; ++it) {
            int f = tid + it * 256;
            int m = f >> 3;
            int g = f & 7;
            int node = m0 + m;
            float4 xv = make_float4(0.f, 0.f, 0.f, 0.f);
            if (node < n) xv = *(const float4*)&x[(size_t)node * NF + k0 + g * 4];
            ushort4 hi, lo;
            hi.x = f2bf(xv.x); lo.x = f2bf(xv.x - bf2f(hi.x));
            hi.y = f2bf(xv.y); lo.y = f2bf(xv.y - bf2f(hi.y));
            hi.z = f2bf(xv.z); lo.z = f2bf(xv.z - bf2f(hi.z));
            hi.w = f2bf(xv.w); lo.w = f2bf(xv.w - bf2f(hi.w));
            int aIdx = ((m >> 4) * 512) + ((((g >> 1) << 4) | (m & 15)) * 8) + (g & 1) * 4;
            *(ushort4*)&Ah[aIdx] = hi;
            *(ushort4*)&Al[aIdx] = lo;
        }
        {
            unsigned short hb[8], lb[8];
            #pragma unroll
            for (int j = 0; j < 8; ++j) {
                float w = W1[(size_t)(k0 + bkq * 8 + j) * NH + bcol];
                hb[j] = f2bf(w);
                lb[j] = f2bf(w - bf2f(hb[j]));
            }
            #pragma unroll
            for (int j = 0; j < 8; ++j) { Bh[bIdx + j] = hb[j]; Bl[bIdx + j] = lb[j]; }
        }
        __syncthreads();
        bf16x8 ah = __builtin_bit_cast(bf16x8, *(short8*)&Ah[wid * 512 + lane * 8]);
        bf16x8 al = __builtin_bit_cast(bf16x8, *(short8*)&Al[wid * 512 + lane * 8]);
        #pragma unroll
        for (int c = 0; c < 4; ++c) {
            bf16x8 bh = __builtin_bit_cast(bf16x8, *(short8*)&Bh[c * 512 + lane * 8]);
            bf16x8 bl = __builtin_bit_cast(bf16x8, *(short8*)&Bl[c * 512 + lane * 8]);
            acc[c] = __builtin_amdgcn_mfma_f32_16x16x32_bf16(ah, bh, acc[c], 0, 0, 0);
            acc[c] = __builtin_amdgcn_mfma_f32_16x16x32_bf16(al, bh, acc[c], 0, 0, 0);
            acc[c] = __builtin_amdgcn_mfma_f32_16x16x32_bf16(ah, bl, acc[c], 0, 0, 0);
        }
        __syncthreads();
    }
    int quad = lane >> 4;
    int cl = lane & 15;
    #pragma unroll
    for (int c = 0; c < 4; ++c) {
        #pragma unroll
        for (int r = 0; r < 4; ++r) {
            int row = m0 + wid * 16 + quad * 4 + r;
            if (row < n) h1[(size_t)row * NH + c * 16 + cl] = __float2half_rn(acc[c][r]);
        }
    }
}

// ---------------- agg1: wave/node, fp16x2 gathers, CONVERGENT pair-split ------
// lanes 0-31 sum even-indexed neighbors, 32-63 odd; lane owns feature pair
// (2*fl, 2*fl+1). Both halves run IDENTICAL trip counts (npair = ceil(cnt/2));
// odd half's phantom element indexes lane==cnt which holds s=0,w=0 -> adds 0.
// Tail padded to 8 with clamped index + zeroed weight. No __shfl under
// lane-dependent control flow (the R6-R8 bug).
__global__ void k_agg1(const __half2* __restrict__ h1, const float* __restrict__ dinv,
                       const int* __restrict__ rowptr_tot, const int* __restrict__ cnt_tot,
                       const int* __restrict__ esrc, const float* __restrict__ wsrc,
                       const float* __restrict__ b1, float* __restrict__ h1agg, int n) {
    int wave = threadIdx.x >> 6;
    int lane = threadIdx.x & 63;
    int v = blockIdx.x * 4 + wave;
    if (v >= n) return;
    int half = lane >> 5;
    int fl = lane & 31;
    float dv = dinv[v];
    float sw = half ? 0.f : dv * dv;
    float2 up = __half22float2(h1[(size_t)v * 32 + fl]);
    float2 acc;
    acc.x = sw * up.x;
    acc.y = sw * up.y;
    int beg = rowptr_tot[v];
    int end = beg + cnt_tot[v];
    for (int base = beg; base < end; base += 64) {
        int cnt = end - base;
        if (cnt > 64) cnt = 64;
        int s = 0;
        float w = 0.f;
        if (lane < cnt) {
            s = esrc[base + lane];
            w = wsrc[base + lane] * dv;
        }
        int npair = (cnt + 1) >> 1;   // UNIFORM across halves (convergent)
        int j = 0;
        for (; j + 8 <= npair; j += 8) {
            __half2 pv[8];
            float ww[8];
            #pragma unroll
            for (int u = 0; u < 8; ++u) {
                int idx = ((j + u) << 1) | half;
                int sj = __shfl(s, idx);
                ww[u] = __shfl(w, idx);
                pv[u] = h1[(size_t)sj * 32 + fl];
            }
            #pragma unroll
            for (int u = 0; u < 8; ++u) {
                float2 f = __half22float2(pv[u]);
                acc.x = fmaf(ww[u], f.x, acc.x);
                acc.y = fmaf(ww[u], f.y, acc.y);
            }
        }
        if (j < npair) {   // convergent padded tail (all lanes, zeroed weights)
            __half2 pv[8];
            float ww[8];
            #pragma unroll
            for (int u = 0; u < 8; ++u) {
                int jj = j + u;
                int idx = (jj << 1) | half;
                int pick = (jj < npair) ? idx : 0;
                int sj = __shfl(s, pick);
                float wv = __shfl(w, pick);
                ww[u] = (jj < npair) ? wv : 0.f;
                pv[u] = h1[(size_t)sj * 32 + fl];
            }
            #pragma unroll
            for (int u = 0; u < 8; ++u) {
                float2 f = __half22float2(pv[u]);
                acc.x = fmaf(ww[u], f.x, acc.x);
                acc.y = fmaf(ww[u], f.y, acc.y);
            }
        }
    }
    acc.x += __shfl(acc.x, fl + 32);
    acc.y += __shfl(acc.y, fl + 32);
    if (half == 0) {
        float2 bb = *(const float2*)&b1[2 * fl];
        float2 o;
        o.x = fmaxf(acc.x + bb.x, 0.f);
        o.y = fmaxf(acc.y + bb.y, 0.f);
        *(float2*)&h1agg[(size_t)v * NH + 2 * fl] = o;
    }
}

// ---------------- GEMM2: g(fp16) = h1agg @ W2   [n,64]x[64,16] ----------------
__global__ void k_gemm2(const float* __restrict__ h1agg, const float* __restrict__ W2,
                        __half* __restrict__ g, int n) {
    __shared__ float W2s[NH * NC];
    {
        int t = threadIdx.x;
        #pragma unroll
        for (int r = 0; r < 4; ++r) W2s[t + r * 256] = W2[t + r * 256];
    }
    __syncthreads();
    int grp = threadIdx.x >> 4;
    int c = threadIdx.x & 15;
    int v = blockIdx.x * 16 + grp;
    if (v >= n) return;
    float acc = 0.f;
    const float* row = &h1agg[(size_t)v * NH];
    #pragma unroll
    for (int k4 = 0; k4 < NH; k4 += 4) {
        float4 h = *(const float4*)&row[k4];
        acc = fmaf(h.x, W2s[(k4 + 0) * NC + c], acc);
        acc = fmaf(h.y, W2s[(k4 + 1) * NC + c], acc);
        acc = fmaf(h.z, W2s[(k4 + 2) * NC + c], acc);
        acc = fmaf(h.w, W2s[(k4 + 3) * NC + c], acc);
    }
    g[(size_t)v * NC + c] = __float2half_rn(acc);
}

// ---------------- agg2 + bias + log_softmax: 16-lane group/node, batch-8 -------
// g table is fp16 (3.2 MB -> near-L2-resident per XCD).
__global__ void k_agg2(const __half* __restrict__ g, const float* __restrict__ dinv,
                       const int* __restrict__ rowptr_tot, const int* __restrict__ cnt_tot,
                       const int* __restrict__ esrc, const float* __restrict__ wsrc,
                       const float* __restrict__ b2, float* __restrict__ out, int n) {
    int grp = threadIdx.x >> 4;
    int lane = threadIdx.x & 15;
    int v = blockIdx.x * 16 + grp;
    if (v >= n) return;
    float dv = dinv[v];
    float acc = dv * dv * __half2float(g[(size_t)v * NC + lane]);
    int beg = rowptr_tot[v];
    int end = beg + cnt_tot[v];
    for (int base = beg; base < end; base += 16) {
        int cnt = end - base;
        if (cnt > 16) cnt = 16;
        int s = 0;
        float w = 0.f;
        if (lane < cnt) {
            s = esrc[base + lane];
            w = wsrc[base + lane] * dv;
        }
        int j = 0;
        for (; j + 8 <= cnt; j += 8) {
            __half vals[8];
            float ww[8];
            #pragma unroll
            for (int u = 0; u < 8; ++u) {
                int sj = __shfl(s, j + u, 16);
                ww[u] = __shfl(w, j + u, 16);
                vals[u] = g[(size_t)sj * NC + lane];
            }
            #pragma unroll
            for (int u = 0; u < 8; ++u) acc = fmaf(ww[u], __half2float(vals[u]), acc);
        }
        if (j < cnt) {
            __half vals[8];
            float ww[8];
            #pragma unroll
            for (int u = 0; u < 8; ++u) {
                int idx = j + u;
                int pick = (idx < cnt) ? idx : 0;
                int sj = __shfl(s, pick, 16);
                float wv = __shfl(w, pick, 16);
                ww[u] = (idx < cnt) ? wv : 0.f;
                vals[u] = g[(size_t)sj * NC + lane];
            }
            #pragma unroll
            for (int u = 0; u < 8; ++u) acc = fmaf(ww[u], __half2float(vals[u]), acc);
        }
    }
    acc += b2[lane];
    float m = acc;
    #pragma unroll
    for (int mask = 1; mask < 16; mask <<= 1)
        m = fmaxf(m, __shfl_xor(m, mask, 16));
    float ex = __expf(acc - m);
    float ssum = ex;
    #pragma unroll
    for (int mask = 1; mask < 16; mask <<= 1)
        ssum += __shfl_xor(ssum, mask, 16);
    out[(size_t)v * NC + lane] = acc - m - __logf(ssum);
}

extern "C" void kernel_launch(void* const* d_in, const int* in_sizes, int n_in,
                              void* d_out, int out_size, void* d_ws, size_t ws_size,
                              hipStream_t stream) {
    const float* x  = (const float*)d_in[0];
    const int*   ei = (const int*)d_in[1];
    const float* W1 = (const float*)d_in[2];
    const float* b1 = (const float*)d_in[3];
    const float* W2 = (const float*)d_in[4];
    const float* b2 = (const float*)d_in[5];
    float* out = (float*)d_out;

    const int N = in_sizes[0] / NF;
    const int E = in_sizes[1] / 2;
    const int* src = ei;
    const int* dst = ei + E;

    const int NB  = (N + 255) >> 8;                       // buckets of 256 nodes
    const int per = (E + NB - 1) / NB;
    const int cap = (per + (per >> 2) + 511) & ~511;      // +25% slack, 512-aligned

    // workspace layout
    char* ws = (char*)d_ws;
    size_t o = 0;
    int*   cnt_tot    = (int*)(ws + o);   o += (size_t)N * 4;
    int*   rowptr_tot = (int*)(ws + o);   o += (size_t)N * 4;
    float* dinv       = (float*)(ws + o); o += (size_t)N * 4;
    int*   bsums      = (int*)(ws + o);   o += 4096;
    int*   bcur       = (int*)(ws + o);   o += (size_t)NBMAX * 4;
    int*   esrc       = (int*)(ws + o);   o += (size_t)E * 4;          // 6.4 MB
    float* wsrc       = (float*)(ws + o); o += (size_t)E * 4;          // 6.4 MB
    __half* h1        = (__half*)(ws + o); o += (size_t)N * NH * 2;    // 12.8 MB fp16
    float* h1agg      = (float*)(ws + o); o += (size_t)N * NH * 4;     // 25.6 MB
    __half* g         = (__half*)h1;     // alias: h1 dead after agg1 (3.2 <= 12.8 MB)
    int*   binned     = (int*)h1agg;     // alias: binned dead before agg1 writes h1agg
                                         // (NB*cap*4 ~ 8.8 MB <= 25.6 MB)

    int gN  = (N + 255) / 256;
    int nbN = (N + 1023) / 1024;
    int nbin = (E + BTILE - 1) / BTILE;

    k_binit<<<(NB + 255) / 256, 256, 0, stream>>>(bcur, NB, cap);
    k_bin<<<nbin, 256, 0, stream>>>(src, dst, bcur, binned, E, NB);
    k_bcount<<<NB, 256, 0, stream>>>(binned, bcur, cnt_tot, cap, N);
    k_dinv<<<gN, 256, 0, stream>>>(cnt_tot, dinv, N);
    k_scan1<<<nbN, 1024, 0, stream>>>(cnt_tot, rowptr_tot, bsums, N);
    k_scan2<<<1, 1024, 0, stream>>>(bsums, nbN);
    k_scan3<<<nbN, 1024, 0, stream>>>(rowptr_tot, bsums, N);
    k_scatter<<<NB, 256, 0, stream>>>(binned, bcur, rowptr_tot, dinv, esrc, wsrc, cap, N);

    k_gemm1<<<(N + 63) / 64, 256, 0, stream>>>(x, W1, h1, N);
    k_agg1<<<(N + 3) / 4, 256, 0, stream>>>((const __half2*)h1, dinv, rowptr_tot, cnt_tot,
                                            esrc, wsrc, b1, h1agg, N);
    k_gemm2<<<(N + 15) / 16, 256, 0, stream>>>(h1agg, W2, g, N);
    k_agg2<<<(N + 15) / 16, 256, 0, stream>>>(g, dinv, rowptr_tot, cnt_tot, esrc, wsrc, b2, out, N);
}